// Round 4
// baseline (1822.922 us; speedup 1.0000x reference)
//
#include <hip/hip_runtime.h>
#include <hip/hip_cooperative_groups.h>
#include <math.h>

namespace cg = cooperative_groups;

typedef __attribute__((ext_vector_type(8))) short bf16x8;
typedef __attribute__((ext_vector_type(4))) float f32x4;

constexpr int NB = 512;
constexpr int NS = 140;
constexpr int NH = 512;
constexpr int NE = 256;
constexpr int NV = 1000;
constexpr int NVP = 1024;   // padded vocab
constexpr int NT = 21;
constexpr int ND = 7;
constexpr int DL = 20;
constexpr int SOS = 2;
constexpr int LSTR = NT + 1;
constexpr int NROW = NT * NB;       // 10752 batched (t,b) rows

__device__ __forceinline__ unsigned short f2bf(float f) {
  union { float f; unsigned u; } v; v.f = f;
  unsigned r = v.u + 0x7fffu + ((v.u >> 16) & 1u);
  return (unsigned short)(r >> 16);
}
__device__ __forceinline__ float bf2f(unsigned short h) {
  union { unsigned u; float f; } v; v.u = ((unsigned)h) << 16;
  return v.f;
}
__device__ __forceinline__ void unp8(uint4 v, float* o) {
  o[0] = bf2f((unsigned short)(v.x & 0xffffu)); o[1] = bf2f((unsigned short)(v.x >> 16));
  o[2] = bf2f((unsigned short)(v.y & 0xffffu)); o[3] = bf2f((unsigned short)(v.y >> 16));
  o[4] = bf2f((unsigned short)(v.z & 0xffffu)); o[5] = bf2f((unsigned short)(v.z >> 16));
  o[6] = bf2f((unsigned short)(v.w & 0xffffu)); o[7] = bf2f((unsigned short)(v.w >> 16));
}

// ---------------------------------------------------------------------------
// 64x64 MFMA tile body, double-buffered LDS (ONE barrier per K-chunk).
// A16: bf16 A. EPI: 0 none, 1 +bias (guarded col<NV), 2 tanh. OUT16: bf16 out.
// ---------------------------------------------------------------------------
template<int A16, int EPI, int OUT16>
__device__ __forceinline__ void gemm_body(
    const float* __restrict__ Af, const unsigned short* __restrict__ Ah,
    const unsigned short* __restrict__ Bt, const float* __restrict__ bias,
    float* __restrict__ C, unsigned short* __restrict__ C16,
    int K, int lda, int ldc, int bx, int by,
    unsigned short* As, unsigned short* Bs)
{
  const int tid = threadIdx.x;
  const int rowBase = by * 64, colBase = bx * 64;
  const int wave = tid >> 6, lane = tid & 63, quad = lane >> 4, l15 = lane & 15;
  const int rw = (wave & 1) * 32, cw = (wave >> 1) * 32;

  f32x4 acc[2][2];
#pragma unroll
  for (int i = 0; i < 2; ++i)
#pragma unroll
    for (int j = 0; j < 2; ++j)
#pragma unroll
      for (int r = 0; r < 4; ++r) acc[i][j][r] = 0.f;

  const int ar = tid >> 2;
  const int kq = (tid & 3) * 8;
  const float* aptrf = nullptr;
  const unsigned short* aptrh = nullptr;
  if (A16) aptrh = Ah + (size_t)(rowBase + ar) * lda + kq;
  else     aptrf = Af + (size_t)(rowBase + ar) * lda + kq;
  const unsigned short* bptr = Bt + (size_t)(colBase + ar) * K + kq;
  unsigned short* asd = &As[ar * 40 + kq];
  unsigned short* bsd = &Bs[ar * 40 + kq];

  float4 x0, x1;
  uint4 av;
  if (A16) {
    av = *(const uint4*)aptrh;
  } else {
    x0 = *(const float4*)aptrf; x1 = *(const float4*)(aptrf + 4);
  }
  uint4 bv = *(const uint4*)bptr;

  int cur = 0;
  for (int k0 = 0; k0 < K; k0 += 32) {
    uint4 aw;
    if (A16) {
      aw = av;
    } else {
      aw.x = (unsigned)f2bf(x0.x) | ((unsigned)f2bf(x0.y) << 16);
      aw.y = (unsigned)f2bf(x0.z) | ((unsigned)f2bf(x0.w) << 16);
      aw.z = (unsigned)f2bf(x1.x) | ((unsigned)f2bf(x1.y) << 16);
      aw.w = (unsigned)f2bf(x1.z) | ((unsigned)f2bf(x1.w) << 16);
    }
    *(uint4*)(asd + cur * 2560) = aw;
    *(uint4*)(bsd + cur * 2560) = bv;

    const int kn = k0 + 32;
    if (kn < K) {
      if (A16) {
        av = *(const uint4*)(aptrh + kn);
      } else {
        x0 = *(const float4*)(aptrf + kn);
        x1 = *(const float4*)(aptrf + kn + 4);
      }
      bv = *(const uint4*)(bptr + kn);
    }
    __syncthreads();

    const unsigned short* Ab = As + cur * 2560;
    const unsigned short* Bb = Bs + cur * 2560;
    const bf16x8 af0 = *(const bf16x8*)&Ab[(rw + l15) * 40 + quad * 8];
    const bf16x8 af1 = *(const bf16x8*)&Ab[(rw + 16 + l15) * 40 + quad * 8];
    const bf16x8 bf0 = *(const bf16x8*)&Bb[(cw + l15) * 40 + quad * 8];
    const bf16x8 bf1 = *(const bf16x8*)&Bb[(cw + 16 + l15) * 40 + quad * 8];
    acc[0][0] = __builtin_amdgcn_mfma_f32_16x16x32_bf16(af0, bf0, acc[0][0], 0, 0, 0);
    acc[0][1] = __builtin_amdgcn_mfma_f32_16x16x32_bf16(af0, bf1, acc[0][1], 0, 0, 0);
    acc[1][0] = __builtin_amdgcn_mfma_f32_16x16x32_bf16(af1, bf0, acc[1][0], 0, 0, 0);
    acc[1][1] = __builtin_amdgcn_mfma_f32_16x16x32_bf16(af1, bf1, acc[1][1], 0, 0, 0);
    cur ^= 1;
  }

#pragma unroll
  for (int i = 0; i < 2; ++i) {
    const int grow = rowBase + rw + 16 * i + quad * 4;
#pragma unroll
    for (int j = 0; j < 2; ++j) {
      const int gcol = colBase + cw + 16 * j + l15;
#pragma unroll
      for (int r = 0; r < 4; ++r) {
        float vo = acc[i][j][r];
        if (EPI == 1) vo += (gcol < NV) ? bias[gcol] : 0.f;
        if (EPI == 2) vo = tanhf(vo);
        if (OUT16) C16[(size_t)(grow + r) * ldc + gcol] = f2bf(vo);
        else       C[(size_t)(grow + r) * ldc + gcol] = vo;
      }
    }
  }
}

template<int A16, int EPI, int OUT16>
__global__ __launch_bounds__(256) void gemm_k(
    const float* __restrict__ Af, const unsigned short* __restrict__ Ah,
    const unsigned short* __restrict__ Bt, const float* __restrict__ bias,
    float* __restrict__ C, unsigned short* __restrict__ C16,
    int K, int lda, int ldc)
{
  __shared__ unsigned short As[2 * 64 * 40];
  __shared__ unsigned short Bs[2 * 64 * 40];
  gemm_body<A16, EPI, OUT16>(Af, Ah, Bt, bias, C, C16, K, lda, ldc,
                             blockIdx.x, blockIdx.y, As, Bs);
}

// ---------------------------------------------------------------------------
// Gi precompute: all 21 steps of emb[dec_t] @ W_ih^T, bf16 out. 2D grid.
// ---------------------------------------------------------------------------
__global__ __launch_bounds__(256) void gemm_gather(
    const float* __restrict__ emb, const unsigned short* __restrict__ Wiht,
    unsigned short* __restrict__ Gi, const int* __restrict__ label)
{
  __shared__ unsigned short As[64 * 40];
  __shared__ unsigned short Bs[64 * 40];
  const int tid = threadIdx.x;
  const int rowBase = blockIdx.y * 64, colBase = blockIdx.x * 64;
  const int wave = tid >> 6, lane = tid & 63, quad = lane >> 4, l15 = lane & 15;
  const int rw = (wave & 1) * 32, cw = (wave >> 1) * 32;
  const int K = 256;

  f32x4 acc[2][2];
#pragma unroll
  for (int i = 0; i < 2; ++i)
#pragma unroll
    for (int j = 0; j < 2; ++j)
#pragma unroll
      for (int r = 0; r < 4; ++r) acc[i][j][r] = 0.f;

  const int ar = tid >> 2;
  const int kq = (tid & 3) * 8;
  const int aRowG = rowBase + ar;
  const int t = aRowG >> 9;
  const int b = aRowG & 511;
  const int dec = (t == 0) ? SOS : label[b * LSTR + (t - 1)];
  const float* aptr = emb + (size_t)dec * NE + kq;
  const unsigned short* bptr = Wiht + (size_t)(colBase + ar) * K + kq;
  unsigned short* asd = &As[ar * 40 + kq];
  unsigned short* bsd = &Bs[ar * 40 + kq];

  float4 x0 = *(const float4*)aptr;
  float4 x1 = *(const float4*)(aptr + 4);
  uint4 bv = *(const uint4*)bptr;

  for (int k0 = 0; k0 < K; k0 += 32) {
    uint4 aw;
    aw.x = (unsigned)f2bf(x0.x) | ((unsigned)f2bf(x0.y) << 16);
    aw.y = (unsigned)f2bf(x0.z) | ((unsigned)f2bf(x0.w) << 16);
    aw.z = (unsigned)f2bf(x1.x) | ((unsigned)f2bf(x1.y) << 16);
    aw.w = (unsigned)f2bf(x1.z) | ((unsigned)f2bf(x1.w) << 16);
    *(uint4*)asd = aw;
    *(uint4*)bsd = bv;
    __syncthreads();
    const int kn = k0 + 32;
    if (kn < K) {
      x0 = *(const float4*)(aptr + kn);
      x1 = *(const float4*)(aptr + kn + 4);
      bv = *(const uint4*)(bptr + kn);
    }
    const bf16x8 af0 = *(const bf16x8*)&As[(rw + l15) * 40 + quad * 8];
    const bf16x8 af1 = *(const bf16x8*)&As[(rw + 16 + l15) * 40 + quad * 8];
    const bf16x8 bf0 = *(const bf16x8*)&Bs[(cw + l15) * 40 + quad * 8];
    const bf16x8 bf1 = *(const bf16x8*)&Bs[(cw + 16 + l15) * 40 + quad * 8];
    acc[0][0] = __builtin_amdgcn_mfma_f32_16x16x32_bf16(af0, bf0, acc[0][0], 0, 0, 0);
    acc[0][1] = __builtin_amdgcn_mfma_f32_16x16x32_bf16(af0, bf1, acc[0][1], 0, 0, 0);
    acc[1][0] = __builtin_amdgcn_mfma_f32_16x16x32_bf16(af1, bf0, acc[1][0], 0, 0, 0);
    acc[1][1] = __builtin_amdgcn_mfma_f32_16x16x32_bf16(af1, bf1, acc[1][1], 0, 0, 0);
    __syncthreads();
  }

#pragma unroll
  for (int i = 0; i < 2; ++i) {
    const int grow = rowBase + rw + 16 * i + quad * 4;
#pragma unroll
    for (int j = 0; j < 2; ++j) {
      const int gcol = colBase + cw + 16 * j + l15;
#pragma unroll
      for (int r = 0; r < 4; ++r)
        Gi[(size_t)(grow + r) * 1536 + gcol] = f2bf(acc[i][j][r]);
    }
  }
}

// ---------------------------------------------------------------------------
// Cooperative recurrent kernel: ALL 22 GRU steps in one launch.
// Grid (8 col-groups, 16 row-tiles) = 128 blocks (1/CU, co-resident).
// Per step: M=32 x N=256 x K=512 GEMM (BK=64, double-buffered, 8 barriers),
// GRU epilogue via LDS gate exchange, u-gate -> U16 (bf16).  grid.sync()
// between steps replaces 22 kernel launches.
// ---------------------------------------------------------------------------
__global__ __launch_bounds__(256) void gru_all(
    float* __restrict__ H_all, const unsigned short* __restrict__ W1pk,
    const unsigned short* __restrict__ Gi,
    const float* __restrict__ b_ih, const float* __restrict__ b_hh,
    unsigned short* __restrict__ U16)
{
  __shared__ __align__(16) char smem[82944];
  unsigned short* As = (unsigned short*)smem;              // 2 x 32 x 72
  unsigned short* Bs = (unsigned short*)(smem + 9216);     // 2 x 256 x 72
  float* Gbuf = (float*)smem;                              // overlay [3][32][72]

  const int tid = threadIdx.x;
  const int wave = tid >> 6, lane = tid & 63, quad = lane >> 4, l15 = lane & 15;
  const int rowBase = blockIdx.y * 32;
  const int colBase = blockIdx.x * 256;
  const int arow = tid >> 3;            // 0..31
  const int akq  = (tid & 7) * 8;       // 8 floats
  const size_t BH = (size_t)NB * NH;
  cg::grid_group grid = cg::this_grid();

  for (int t = 0; t <= NT; ++t) {
    const float* Ht = H_all + (size_t)t * BH;
    float* Hn = H_all + (size_t)(t + 1) * BH;
    const unsigned short* Gt = Gi + (size_t)((t < NT) ? t : 0) * NB * 1536;
    unsigned short* Ut = U16 + (size_t)t * BH;
    const int notLast = (t < NT) ? 1 : 0;

    f32x4 acc[2][4];
#pragma unroll
    for (int i = 0; i < 2; ++i)
#pragma unroll
      for (int j = 0; j < 4; ++j)
#pragma unroll
        for (int r = 0; r < 4; ++r) acc[i][j][r] = 0.f;

    const float* aptr = Ht + (size_t)(rowBase + arow) * NH + akq;
    const unsigned short* bptr = W1pk + ((size_t)colBase + tid) * 64;

    float4 xa0 = *(const float4*)aptr;
    float4 xa1 = *(const float4*)(aptr + 4);
    uint4 bv[8];
#pragma unroll
    for (int q = 0; q < 8; ++q) bv[q] = ((const uint4*)bptr)[q];

    int cur = 0;
    for (int c = 0; c < 8; ++c) {
      uint4 aw;
      aw.x = (unsigned)f2bf(xa0.x) | ((unsigned)f2bf(xa0.y) << 16);
      aw.y = (unsigned)f2bf(xa0.z) | ((unsigned)f2bf(xa0.w) << 16);
      aw.z = (unsigned)f2bf(xa1.x) | ((unsigned)f2bf(xa1.y) << 16);
      aw.w = (unsigned)f2bf(xa1.z) | ((unsigned)f2bf(xa1.w) << 16);
      *(uint4*)&As[((cur << 5) + arow) * 72 + akq] = aw;
      {
        unsigned short* bd = &Bs[((cur << 8) + tid) * 72];
#pragma unroll
        for (int q = 0; q < 8; ++q) ((uint4*)bd)[q] = bv[q];
      }
      const int cn = c + 1;
      if (cn < 8) {
        const float* ap = aptr + cn * 64;
        xa0 = *(const float4*)ap;
        xa1 = *(const float4*)(ap + 4);
        const unsigned short* bp = bptr + (size_t)cn * (2048 * 64);
#pragma unroll
        for (int q = 0; q < 8; ++q) bv[q] = ((const uint4*)bp)[q];
      }
      __syncthreads();

      const unsigned short* Ab = As + (cur << 5) * 72;
      const unsigned short* Bb = Bs + (cur << 8) * 72;
#pragma unroll
      for (int kk = 0; kk < 2; ++kk) {
        const bf16x8 af0 = *(const bf16x8*)&Ab[(l15) * 72 + kk * 32 + quad * 8];
        const bf16x8 af1 = *(const bf16x8*)&Ab[(16 + l15) * 72 + kk * 32 + quad * 8];
#pragma unroll
        for (int j = 0; j < 4; ++j) {
          const bf16x8 bf = *(const bf16x8*)&Bb[(wave * 64 + j * 16 + l15) * 72 + kk * 32 + quad * 8];
          acc[0][j] = __builtin_amdgcn_mfma_f32_16x16x32_bf16(af0, bf, acc[0][j], 0, 0, 0);
          acc[1][j] = __builtin_amdgcn_mfma_f32_16x16x32_bf16(af1, bf, acc[1][j], 0, 0, 0);
        }
      }
      cur ^= 1;
    }
    __syncthreads();   // all LDS reads done before Gbuf overlay writes

    // gates r,z,n -> Gbuf (waves 0..2); u-gate -> U16 bf16 (wave 3)
#pragma unroll
    for (int i = 0; i < 2; ++i) {
#pragma unroll
      for (int j = 0; j < 4; ++j) {
#pragma unroll
        for (int r = 0; r < 4; ++r) {
          const int rl = 16 * i + quad * 4 + r;
          const int col = j * 16 + l15;
          if (wave == 3)
            Ut[(size_t)(rowBase + rl) * NH + blockIdx.x * 64 + col] = f2bf(acc[i][j][r]);
          else
            Gbuf[(wave * 32 + rl) * 72 + col] = acc[i][j][r];
        }
      }
    }
    __syncthreads();

    if (notLast) {
      const int rl = tid >> 3, c8 = (tid & 7) * 8;
      const int bg = rowBase + rl;
      const int jg = blockIdx.x * 64 + c8;
      const float* g0 = Gbuf + (0 * 32 + rl) * 72 + c8;
      const float* g1 = Gbuf + (1 * 32 + rl) * 72 + c8;
      const float* g2 = Gbuf + (2 * 32 + rl) * 72 + c8;
      const unsigned short* gp = Gt + (size_t)bg * 1536;
      float gr[8], gz[8], gn[8];
      { uint4 a = *(const uint4*)(gp + jg);        unp8(a, gr); }
      { uint4 a = *(const uint4*)(gp + 512 + jg);  unp8(a, gz); }
      { uint4 a = *(const uint4*)(gp + 1024 + jg); unp8(a, gn); }
      const float* hR = Ht + (size_t)bg * NH + jg;
      float* hW = Hn + (size_t)bg * NH + jg;
      const float4 ho0 = *(const float4*)hR;
      const float4 ho1 = *(const float4*)(hR + 4);
      const float hov[8] = {ho0.x, ho0.y, ho0.z, ho0.w, ho1.x, ho1.y, ho1.z, ho1.w};
      float o[8];
#pragma unroll
      for (int c = 0; c < 8; ++c) {
        const int j = jg + c;
        const float ir  = gr[c] + b_ih[j];
        const float iz  = gz[c] + b_ih[512 + j];
        const float inn = gn[c] + b_ih[1024 + j];
        const float hr  = g0[c] + b_hh[j];
        const float hz  = g1[c] + b_hh[512 + j];
        const float hn  = g2[c] + b_hh[1024 + j];
        const float rg = 1.f / (1.f + expf(-(ir + hr)));
        const float zg = 1.f / (1.f + expf(-(iz + hz)));
        const float ng = tanhf(inn + rg * hn);
        o[c] = (1.f - zg) * ng + zg * hov[c];
      }
      *(float4*)hW = make_float4(o[0], o[1], o[2], o[3]);
      *(float4*)(hW + 4) = make_float4(o[4], o[5], o[6], o[7]);
    }
    __threadfence();
    grid.sync();
  }
}

// ---------------------------------------------------------------------------
// MFMA day attention, one block per (b,d).  bf16 Q from U16 (no conversion),
// two-phase E staging: global->Erow coalesced, then Erow->ETs with
// s-consecutive mapping (conflict-free transposed writes).  ~75 KB LDS,
// 2 blocks/CU, 3 barriers.
// ---------------------------------------------------------------------------
__global__ __launch_bounds__(256) void day_attn_mfma(
    const float* __restrict__ enc, const int* __restrict__ numpairs,
    const unsigned short* __restrict__ U16, unsigned short* __restrict__ week)
{
  __shared__ unsigned short Erow[32 * 520];   // [s][h] (rows>=20 garbage, cols unread)
  __shared__ unsigned short ETs[512 * 36];    // [h][s], cols 20..31 zeroed
  __shared__ float S_lds[32 * 33];
  __shared__ unsigned short P_lds[32 * 40];

  const int tid = threadIdx.x;
  const int wave = tid >> 6, lane = tid & 63;
  const int quad = lane >> 4, l15 = lane & 15;
  const int b = blockIdx.x / ND, d = blockIdx.x % ND;
  const int mt = wave >> 1, nt = wave & 1;

  // zero ETs pad cols 20..31 (6 u32 per row) and all of P_lds
  for (int i = tid; i < 512 * 6; i += 256)
    *(unsigned*)&ETs[(i / 6) * 36 + 20 + (i % 6) * 2] = 0;
  for (int i = tid; i < 640; i += 256) ((unsigned*)P_lds)[i] = 0;

  // stage E_d row-major (coalesced f32 reads, bf16 LDS)
  const float* eb = enc + ((size_t)b * NS + d * DL) * NH;
  for (int f = tid; f < DL * NH / 4; f += 256) {
    const int s = f >> 7, h = (f & 127) * 4;
    const float4 v = *(const float4*)(eb + s * NH + h);
    ushort4 hs;
    hs.x = f2bf(v.x); hs.y = f2bf(v.y); hs.z = f2bf(v.z); hs.w = f2bf(v.w);
    *(ushort4*)&Erow[s * 520 + h] = hs;
  }

  // Q fragments straight from bf16 U16: row m = mt*16+l15 -> t (clamped)
  bf16x8 qa[16];
  {
    const int m = mt * 16 + l15;
    const int t = (m < NT + 1) ? m : NT;
    const unsigned short* qp = U16 + ((size_t)t * NB + b) * NH + quad * 8;
#pragma unroll
    for (int ks = 0; ks < 16; ++ks)
      qa[ks] = *(const bf16x8*)(qp + ks * 32);
  }
  __syncthreads();

  // build ETs from Erow: consecutive lanes take consecutive s -> writes are
  // byte-consecutive (no bank conflicts)
  for (int i = tid; i < 64 * DL; i += 256) {
    const int s = i % DL, h8 = i / DL;
    const uint4 v = *(const uint4*)&Erow[s * 520 + h8 * 8];
    const unsigned short* u = (const unsigned short*)&v;
#pragma unroll
    for (int c = 0; c < 8; ++c)
      ETs[(h8 * 8 + c) * 36 + s] = u[c];
  }

  // ---- QK^T : wave (mt,nt) computes a 16x16 S tile; B = row-major Erow ----
  f32x4 sacc = {0.f, 0.f, 0.f, 0.f};
#pragma unroll
  for (int ks = 0; ks < 16; ++ks) {
    const bf16x8 bf = *(const bf16x8*)&Erow[(nt * 16 + l15) * 520 + ks * 32 + quad * 8];
    sacc = __builtin_amdgcn_mfma_f32_16x16x32_bf16(qa[ks], bf, sacc, 0, 0, 0);
  }
#pragma unroll
  for (int r = 0; r < 4; ++r)
    S_lds[(mt * 16 + quad * 4 + r) * 33 + nt * 16 + l15] = sacc[r];
  __syncthreads();

  // ---- masked softmax over s (8 threads per row) ----
  {
    const int r = tid >> 3, c = tid & 7;
    const int base = b * NS + d * DL;
    float v0 = S_lds[r * 33 + c];
    if (numpairs[base + c] == 0) v0 = -1e9f;
    float v1 = S_lds[r * 33 + c + 8];
    if (numpairs[base + c + 8] == 0) v1 = -1e9f;
    float v2 = -1e30f;
    if (c < 4) {
      v2 = S_lds[r * 33 + c + 16];
      if (numpairs[base + c + 16] == 0) v2 = -1e9f;
    }
    float mx = fmaxf(fmaxf(v0, v1), v2);
    mx = fmaxf(mx, __shfl_xor(mx, 1));
    mx = fmaxf(mx, __shfl_xor(mx, 2));
    mx = fmaxf(mx, __shfl_xor(mx, 4));
    const float e0 = expf(v0 - mx), e1 = expf(v1 - mx);
    const float e2 = (c < 4) ? expf(v2 - mx) : 0.f;
    float sm = e0 + e1 + e2;
    sm += __shfl_xor(sm, 1);
    sm += __shfl_xor(sm, 2);
    sm += __shfl_xor(sm, 4);
    const float inv = 1.f / sm;
    P_lds[r * 40 + c] = f2bf(e0 * inv);
    P_lds[r * 40 + c + 8] = f2bf(e1 * inv);
    if (c < 4) P_lds[r * 40 + c + 16] = f2bf(e2 * inv);
  }
  __syncthreads();

  // ---- PV : wave (mt,nt) covers rows mt*16, h-cols nt*256 .. +255 ----
  const bf16x8 pa = *(const bf16x8*)&P_lds[(mt * 16 + l15) * 40 + quad * 8];
#pragma unroll
  for (int j = 0; j < 16; ++j) {
    const int hcol = nt * 256 + j * 16;
    const bf16x8 bf = *(const bf16x8*)&ETs[(hcol + l15) * 36 + quad * 8];
    f32x4 oacc = {0.f, 0.f, 0.f, 0.f};
    oacc = __builtin_amdgcn_mfma_f32_16x16x32_bf16(pa, bf, oacc, 0, 0, 0);
#pragma unroll
    for (int r = 0; r < 4; ++r) {
      const int t = mt * 16 + quad * 4 + r;
      if (t < NT)
        week[(((size_t)t * NB + b) * ND + d) * NH + hcol + l15] = f2bf(oacc[r]);
    }
  }
}

// ---------------------------------------------------------------------------
// Batched week attention + ctx + concat.  One block = (t, 16 b's).
// U is bf16 now.
// ---------------------------------------------------------------------------
__global__ __launch_bounds__(256) void wk_ctx(
    const unsigned short* __restrict__ U16, const unsigned short* __restrict__ week,
    const float* __restrict__ H, unsigned short* __restrict__ concat)
{
  __shared__ float scS[16 * ND];
  __shared__ float awS[16 * ND];
  const int tid = threadIdx.x;
  const int t = blockIdx.x >> 5;
  const int grp = blockIdx.x & 31;
  const int b16 = tid >> 4, k16 = tid & 15;
  const int b = grp * 16 + b16;
  const unsigned short* vp = U16 + ((size_t)(t + 1) * NB + b) * NH + k16 * 32;
  const size_t wrow = ((size_t)t * NB + b) * ND;

  float va[32];
#pragma unroll
  for (int q = 0; q < 4; ++q) {
    const uint4 av = ((const uint4*)vp)[q];
    unp8(av, va + q * 8);
  }

  for (int d = 0; d < ND; ++d) {
    const unsigned short* wp = week + (wrow + d) * NH + k16 * 32;
    float p = 0.f;
#pragma unroll
    for (int q = 0; q < 4; ++q) {
      const uint4 wv = ((const uint4*)wp)[q];
      float w8[8];
      unp8(wv, w8);
#pragma unroll
      for (int c = 0; c < 8; ++c) p += va[q * 8 + c] * w8[c];
    }
    p += __shfl_down(p, 8); p += __shfl_down(p, 4);
    p += __shfl_down(p, 2); p += __shfl_down(p, 1);
    if (k16 == 0) scS[b16 * ND + d] = p;
  }
  __syncthreads();
  if (tid < 16) {
    float s[ND], mx = -1e30f;
    for (int d = 0; d < ND; ++d) { s[d] = scS[tid * ND + d]; mx = fmaxf(mx, s[d]); }
    float sum = 0.f;
    for (int d = 0; d < ND; ++d) { float e = expf(s[d] - mx); s[d] = e; sum += e; }
    const float inv = 1.f / sum;
    for (int d = 0; d < ND; ++d) awS[tid * ND + d] = s[d] * inv;
  }
  __syncthreads();

  const int c0 = k16 * 32;
  const float* hp = H + ((size_t)(t + 1) * NB + b) * NH + c0;
  float aw[ND];
#pragma unroll
  for (int d = 0; d < ND; ++d) aw[d] = awS[b16 * ND + d];
  unsigned short* crow = concat + ((size_t)t * NB + b) * 1024;
#pragma unroll
  for (int q = 0; q < 8; ++q) {
    const int c = c0 + q * 4;
    const float4 hv = *(const float4*)(hp + q * 4);
    ushort4 hs;
    hs.x = f2bf(hv.x); hs.y = f2bf(hv.y); hs.z = f2bf(hv.z); hs.w = f2bf(hv.w);
    *(ushort4*)(crow + c) = hs;
    float4 cv = make_float4(0.f, 0.f, 0.f, 0.f);
#pragma unroll
    for (int d = 0; d < ND; ++d) {
      const ushort4 wv = *(const ushort4*)(week + (wrow + d) * NH + c);
      cv.x += aw[d] * bf2f(wv.x); cv.y += aw[d] * bf2f(wv.y);
      cv.z += aw[d] * bf2f(wv.z); cv.w += aw[d] * bf2f(wv.w);
    }
    ushort4 cs;
    cs.x = f2bf(cv.x); cs.y = f2bf(cv.y); cs.z = f2bf(cv.z); cs.w = f2bf(cv.w);
    *(ushort4*)(crow + 512 + c) = cs;
  }
}

// ---------------------------------------------------------------------------
// Single-pass log_softmax, row in registers.  Row r = t*NB+b -> out[b,t,:].
// ---------------------------------------------------------------------------
__global__ __launch_bounds__(256) void lsm_k(
    const float* __restrict__ logits, float* __restrict__ out)
{
  __shared__ float red[8];
  const int tid = threadIdx.x;
  const int wave = tid >> 6, lane = tid & 63;
  const int r = blockIdx.x;
  const int t = r >> 9, b = r & (NB - 1);
  const float* row = logits + (size_t)r * NVP;
  float v[4];
  float mx = -1e30f;
#pragma unroll
  for (int k = 0; k < 4; ++k) {
    const int c = tid + k * 256;
    v[k] = row[c];
    if (c < NV) mx = fmaxf(mx, v[k]);
  }
#pragma unroll
  for (int off = 32; off; off >>= 1) mx = fmaxf(mx, __shfl_xor(mx, off));
  if (lane == 0) red[wave] = mx;
  __syncthreads();
  mx = fmaxf(fmaxf(red[0], red[1]), fmaxf(red[2], red[3]));
  float s = 0.f;
#pragma unroll
  for (int k = 0; k < 4; ++k) {
    const int c = tid + k * 256;
    if (c < NV) s += expf(v[k] - mx);
  }
#pragma unroll
  for (int off = 32; off; off >>= 1) s += __shfl_xor(s, off);
  if (lane == 0) red[4 + wave] = s;
  __syncthreads();
  const float lse = mx + logf(red[4] + red[5] + red[6] + red[7]);
  float* orow = out + ((size_t)b * NT + t) * NV;
#pragma unroll
  for (int k = 0; k < 4; ++k) {
    const int c = tid + k * 256;
    if (c < NV) orow[c] = v[k] - lse;
  }
}

__global__ void write_last(const int* __restrict__ label, float* __restrict__ out2)
{
  const int b = blockIdx.x * 256 + threadIdx.x;
  if (b < NB) out2[b] = (float)label[b * LSTR + (NT - 1)];
}

// W1pk[(k/64)][n'][k%64]: n' = g*256 + gate*64 + (j - g*64); gate 0..2 =
// W_hh gates, gate 3 = Wa^T (u-gate).  k-chunked (64) for coalesced staging.
__global__ __launch_bounds__(256) void pack_w1pk(
    const float* __restrict__ Whh, const float* __restrict__ Wa,
    unsigned short* __restrict__ W1pk)
{
  const int idx = blockIdx.x * 256 + threadIdx.x;
  const int np = idx >> 9, k = idx & 511;
  const int g = np >> 8, rem = np & 255, gate = rem >> 6, j = g * 64 + (rem & 63);
  float v;
  if (gate < 3) v = Whh[(size_t)(gate * 512 + j) * 512 + k];
  else          v = Wa[(size_t)k * 512 + j];
  W1pk[((size_t)(k >> 6) * 2048 + np) * 64 + (k & 63)] = f2bf(v);
}

__global__ __launch_bounds__(256) void cast4(
    const float4* __restrict__ in, ushort4* __restrict__ out, int n4)
{
  const int i = blockIdx.x * 256 + threadIdx.x;
  if (i < n4) {
    const float4 x = in[i];
    ushort4 r;
    r.x = f2bf(x.x); r.y = f2bf(x.y); r.z = f2bf(x.z); r.w = f2bf(x.w);
    out[i] = r;
  }
}

extern "C" void kernel_launch(void* const* d_in, const int* in_sizes, int n_in,
                              void* d_out, int out_size, void* d_ws, size_t ws_size,
                              hipStream_t stream)
{
  const float* enc_h  = (const float*)d_in[0];
  const float* enc    = (const float*)d_in[1];
  const int*   label  = (const int*)d_in[2];
  const int*   numprs = (const int*)d_in[3];
  const float* emb    = (const float*)d_in[4];
  const float* W_ih   = (const float*)d_in[5];
  const float* W_hh   = (const float*)d_in[6];
  const float* b_ih   = (const float*)d_in[7];
  const float* b_hh   = (const float*)d_in[8];
  const float* Wa     = (const float*)d_in[9];
  const float* wa_W   = (const float*)d_in[10];
  const float* fc_W   = (const float*)d_in[11];
  const float* fc_b   = (const float*)d_in[12];
  float* out = (float*)d_out;

  float* f = (float*)d_ws;
  float* H_all   = f; f += (size_t)(NT + 1) * NB * NH;   // 22 hidden states
  float* logitsW = f; f += (size_t)NROW * NVP;
  unsigned short* us = (unsigned short*)f;
  unsigned short* U16    = us; us += (size_t)(NT + 1) * NB * NH;
  unsigned short* W1pk   = us; us += (size_t)2048 * 512;
  unsigned short* W3t    = us; us += (size_t)512 * 1024;
  unsigned short* W4t    = us; us += (size_t)NVP * 512;
  unsigned short* Wiht   = us; us += (size_t)1536 * 256;
  unsigned short* Gi     = us; us += (size_t)NT * NB * 1536;
  unsigned short* week   = us; us += (size_t)NT * NB * ND * NH;
  unsigned short* concatW= us; us += (size_t)NROW * 1024;
  unsigned short* aBuf   = us; us += (size_t)NROW * 512;

  const dim3 blk(256);
  const size_t BH = (size_t)NB * NH;

  hipMemcpyAsync(H_all, enc_h, BH * sizeof(float),
                 hipMemcpyDeviceToDevice, stream);

  // --- setup: weight packs/casts + Gi precompute ---
  pack_w1pk<<<dim3(2048 * 512 / 256), blk, 0, stream>>>(W_hh, Wa, W1pk);
  cast4<<<dim3(512 * 1024 / 4 / 256), blk, 0, stream>>>(
      (const float4*)wa_W, (ushort4*)W3t, 512 * 1024 / 4);
  cast4<<<dim3((NV * 512 / 4 + 255) / 256), blk, 0, stream>>>(
      (const float4*)fc_W, (ushort4*)W4t, NV * 512 / 4);
  hipMemsetAsync(W4t + (size_t)NV * 512, 0, (size_t)(NVP - NV) * 512 * 2, stream);
  cast4<<<dim3(1536 * 256 / 4 / 256), blk, 0, stream>>>(
      (const float4*)W_ih, (ushort4*)Wiht, 1536 * 256 / 4);
  gemm_gather<<<dim3(24, NT * 8), blk, 0, stream>>>(emb, Wiht, Gi, label);

  // --- recurrent phase: single cooperative kernel, all 22 steps ---
  {
    void* args[] = {&H_all, &W1pk, &Gi, (void*)&b_ih, (void*)&b_hh, &U16};
    hipLaunchCooperativeKernel((void*)gru_all, dim3(8, 16), blk, args, 0, stream);
  }

  // --- batched tail ---
  day_attn_mfma<<<dim3(NB * ND), blk, 0, stream>>>(enc, numprs, U16, week);
  wk_ctx<<<dim3(NT * 32), blk, 0, stream>>>(U16, week, H_all, concatW);
  gemm_k<1, 2, 1><<<dim3(8, NROW / 64), blk, 0, stream>>>(
      nullptr, concatW, W3t, nullptr, nullptr, aBuf, 1024, 1024, 512);
  gemm_k<1, 1, 0><<<dim3(16, NROW / 64), blk, 0, stream>>>(
      nullptr, aBuf, W4t, fc_b, logitsW, nullptr, 512, 512, NVP);
  lsm_k<<<dim3(NROW), blk, 0, stream>>>(logitsW, out);
  write_last<<<dim3(2), blk, 0, stream>>>(label, out + (size_t)NB * NT * NV);
}

// Round 6
// 784.760 us; speedup vs baseline: 2.3229x; 2.3229x over previous
//
#include <hip/hip_runtime.h>
#include <math.h>

typedef __attribute__((ext_vector_type(8))) short bf16x8;
typedef __attribute__((ext_vector_type(4))) float f32x4;

constexpr int NB = 512;
constexpr int NS = 140;
constexpr int NH = 512;
constexpr int NE = 256;
constexpr int NV = 1000;
constexpr int NVP = 1024;   // padded vocab
constexpr int NT = 21;
constexpr int ND = 7;
constexpr int DL = 20;
constexpr int SOS = 2;
constexpr int LSTR = NT + 1;
constexpr int NROW = NT * NB;       // 10752 batched (t,b) rows

__device__ __forceinline__ unsigned short f2bf(float f) {
  union { float f; unsigned u; } v; v.f = f;
  unsigned r = v.u + 0x7fffu + ((v.u >> 16) & 1u);
  return (unsigned short)(r >> 16);
}
__device__ __forceinline__ float bf2f(unsigned short h) {
  union { unsigned u; float f; } v; v.u = ((unsigned)h) << 16;
  return v.f;
}
__device__ __forceinline__ void unp8(uint4 v, float* o) {
  o[0] = bf2f((unsigned short)(v.x & 0xffffu)); o[1] = bf2f((unsigned short)(v.x >> 16));
  o[2] = bf2f((unsigned short)(v.y & 0xffffu)); o[3] = bf2f((unsigned short)(v.y >> 16));
  o[4] = bf2f((unsigned short)(v.z & 0xffffu)); o[5] = bf2f((unsigned short)(v.z >> 16));
  o[6] = bf2f((unsigned short)(v.w & 0xffffu)); o[7] = bf2f((unsigned short)(v.w >> 16));
}

// ---------------------------------------------------------------------------
// 64x64 MFMA tile body, double-buffered LDS (ONE barrier per K-chunk).
// A16: bf16 A. EPI: 0 none, 1 +bias (guarded col<NV), 2 tanh. OUT16: bf16 out.
// ---------------------------------------------------------------------------
template<int A16, int EPI, int OUT16>
__device__ __forceinline__ void gemm_body(
    const float* __restrict__ Af, const unsigned short* __restrict__ Ah,
    const unsigned short* __restrict__ Bt, const float* __restrict__ bias,
    float* __restrict__ C, unsigned short* __restrict__ C16,
    int K, int lda, int ldc, int bx, int by,
    unsigned short* As, unsigned short* Bs)
{
  const int tid = threadIdx.x;
  const int rowBase = by * 64, colBase = bx * 64;
  const int wave = tid >> 6, lane = tid & 63, quad = lane >> 4, l15 = lane & 15;
  const int rw = (wave & 1) * 32, cw = (wave >> 1) * 32;

  f32x4 acc[2][2];
#pragma unroll
  for (int i = 0; i < 2; ++i)
#pragma unroll
    for (int j = 0; j < 2; ++j)
#pragma unroll
      for (int r = 0; r < 4; ++r) acc[i][j][r] = 0.f;

  const int ar = tid >> 2;
  const int kq = (tid & 3) * 8;
  const float* aptrf = nullptr;
  const unsigned short* aptrh = nullptr;
  if (A16) aptrh = Ah + (size_t)(rowBase + ar) * lda + kq;
  else     aptrf = Af + (size_t)(rowBase + ar) * lda + kq;
  const unsigned short* bptr = Bt + (size_t)(colBase + ar) * K + kq;
  unsigned short* asd = &As[ar * 40 + kq];
  unsigned short* bsd = &Bs[ar * 40 + kq];

  float4 x0, x1;
  uint4 av;
  if (A16) {
    av = *(const uint4*)aptrh;
  } else {
    x0 = *(const float4*)aptrf; x1 = *(const float4*)(aptrf + 4);
  }
  uint4 bv = *(const uint4*)bptr;

  int cur = 0;
  for (int k0 = 0; k0 < K; k0 += 32) {
    uint4 aw;
    if (A16) {
      aw = av;
    } else {
      aw.x = (unsigned)f2bf(x0.x) | ((unsigned)f2bf(x0.y) << 16);
      aw.y = (unsigned)f2bf(x0.z) | ((unsigned)f2bf(x0.w) << 16);
      aw.z = (unsigned)f2bf(x1.x) | ((unsigned)f2bf(x1.y) << 16);
      aw.w = (unsigned)f2bf(x1.z) | ((unsigned)f2bf(x1.w) << 16);
    }
    *(uint4*)(asd + cur * 2560) = aw;
    *(uint4*)(bsd + cur * 2560) = bv;

    const int kn = k0 + 32;
    if (kn < K) {
      if (A16) {
        av = *(const uint4*)(aptrh + kn);
      } else {
        x0 = *(const float4*)(aptrf + kn);
        x1 = *(const float4*)(aptrf + kn + 4);
      }
      bv = *(const uint4*)(bptr + kn);
    }
    __syncthreads();

    const unsigned short* Ab = As + cur * 2560;
    const unsigned short* Bb = Bs + cur * 2560;
    const bf16x8 af0 = *(const bf16x8*)&Ab[(rw + l15) * 40 + quad * 8];
    const bf16x8 af1 = *(const bf16x8*)&Ab[(rw + 16 + l15) * 40 + quad * 8];
    const bf16x8 bf0 = *(const bf16x8*)&Bb[(cw + l15) * 40 + quad * 8];
    const bf16x8 bf1 = *(const bf16x8*)&Bb[(cw + 16 + l15) * 40 + quad * 8];
    acc[0][0] = __builtin_amdgcn_mfma_f32_16x16x32_bf16(af0, bf0, acc[0][0], 0, 0, 0);
    acc[0][1] = __builtin_amdgcn_mfma_f32_16x16x32_bf16(af0, bf1, acc[0][1], 0, 0, 0);
    acc[1][0] = __builtin_amdgcn_mfma_f32_16x16x32_bf16(af1, bf0, acc[1][0], 0, 0, 0);
    acc[1][1] = __builtin_amdgcn_mfma_f32_16x16x32_bf16(af1, bf1, acc[1][1], 0, 0, 0);
    cur ^= 1;
  }

#pragma unroll
  for (int i = 0; i < 2; ++i) {
    const int grow = rowBase + rw + 16 * i + quad * 4;
#pragma unroll
    for (int j = 0; j < 2; ++j) {
      const int gcol = colBase + cw + 16 * j + l15;
#pragma unroll
      for (int r = 0; r < 4; ++r) {
        float vo = acc[i][j][r];
        if (EPI == 1) vo += (gcol < NV) ? bias[gcol] : 0.f;
        if (EPI == 2) vo = tanhf(vo);
        if (OUT16) C16[(size_t)(grow + r) * ldc + gcol] = f2bf(vo);
        else       C[(size_t)(grow + r) * ldc + gcol] = vo;
      }
    }
  }
}

template<int A16, int EPI, int OUT16>
__global__ __launch_bounds__(256) void gemm_k(
    const float* __restrict__ Af, const unsigned short* __restrict__ Ah,
    const unsigned short* __restrict__ Bt, const float* __restrict__ bias,
    float* __restrict__ C, unsigned short* __restrict__ C16,
    int K, int lda, int ldc)
{
  __shared__ unsigned short As[2 * 64 * 40];
  __shared__ unsigned short Bs[2 * 64 * 40];
  gemm_body<A16, EPI, OUT16>(Af, Ah, Bt, bias, C, C16, K, lda, ldc,
                             blockIdx.x, blockIdx.y, As, Bs);
}

// ---------------------------------------------------------------------------
// Gi precompute: all 21 steps of emb[dec_t] @ W_ih^T, bf16 out. 2D grid.
// ---------------------------------------------------------------------------
__global__ __launch_bounds__(256) void gemm_gather(
    const float* __restrict__ emb, const unsigned short* __restrict__ Wiht,
    unsigned short* __restrict__ Gi, const int* __restrict__ label)
{
  __shared__ unsigned short As[64 * 40];
  __shared__ unsigned short Bs[64 * 40];
  const int tid = threadIdx.x;
  const int rowBase = blockIdx.y * 64, colBase = blockIdx.x * 64;
  const int wave = tid >> 6, lane = tid & 63, quad = lane >> 4, l15 = lane & 15;
  const int rw = (wave & 1) * 32, cw = (wave >> 1) * 32;
  const int K = 256;

  f32x4 acc[2][2];
#pragma unroll
  for (int i = 0; i < 2; ++i)
#pragma unroll
    for (int j = 0; j < 2; ++j)
#pragma unroll
      for (int r = 0; r < 4; ++r) acc[i][j][r] = 0.f;

  const int ar = tid >> 2;
  const int kq = (tid & 3) * 8;
  const int aRowG = rowBase + ar;
  const int t = aRowG >> 9;
  const int b = aRowG & 511;
  const int dec = (t == 0) ? SOS : label[b * LSTR + (t - 1)];
  const float* aptr = emb + (size_t)dec * NE + kq;
  const unsigned short* bptr = Wiht + (size_t)(colBase + ar) * K + kq;
  unsigned short* asd = &As[ar * 40 + kq];
  unsigned short* bsd = &Bs[ar * 40 + kq];

  float4 x0 = *(const float4*)aptr;
  float4 x1 = *(const float4*)(aptr + 4);
  uint4 bv = *(const uint4*)bptr;

  for (int k0 = 0; k0 < K; k0 += 32) {
    uint4 aw;
    aw.x = (unsigned)f2bf(x0.x) | ((unsigned)f2bf(x0.y) << 16);
    aw.y = (unsigned)f2bf(x0.z) | ((unsigned)f2bf(x0.w) << 16);
    aw.z = (unsigned)f2bf(x1.x) | ((unsigned)f2bf(x1.y) << 16);
    aw.w = (unsigned)f2bf(x1.z) | ((unsigned)f2bf(x1.w) << 16);
    *(uint4*)asd = aw;
    *(uint4*)bsd = bv;
    __syncthreads();
    const int kn = k0 + 32;
    if (kn < K) {
      x0 = *(const float4*)(aptr + kn);
      x1 = *(const float4*)(aptr + kn + 4);
      bv = *(const uint4*)(bptr + kn);
    }
    const bf16x8 af0 = *(const bf16x8*)&As[(rw + l15) * 40 + quad * 8];
    const bf16x8 af1 = *(const bf16x8*)&As[(rw + 16 + l15) * 40 + quad * 8];
    const bf16x8 bf0 = *(const bf16x8*)&Bs[(cw + l15) * 40 + quad * 8];
    const bf16x8 bf1 = *(const bf16x8*)&Bs[(cw + 16 + l15) * 40 + quad * 8];
    acc[0][0] = __builtin_amdgcn_mfma_f32_16x16x32_bf16(af0, bf0, acc[0][0], 0, 0, 0);
    acc[0][1] = __builtin_amdgcn_mfma_f32_16x16x32_bf16(af0, bf1, acc[0][1], 0, 0, 0);
    acc[1][0] = __builtin_amdgcn_mfma_f32_16x16x32_bf16(af1, bf0, acc[1][0], 0, 0, 0);
    acc[1][1] = __builtin_amdgcn_mfma_f32_16x16x32_bf16(af1, bf1, acc[1][1], 0, 0, 0);
    __syncthreads();
  }

#pragma unroll
  for (int i = 0; i < 2; ++i) {
    const int grow = rowBase + rw + 16 * i + quad * 4;
#pragma unroll
    for (int j = 0; j < 2; ++j) {
      const int gcol = colBase + cw + 16 * j + l15;
#pragma unroll
      for (int r = 0; r < 4; ++r)
        Gi[(size_t)(grow + r) * 1536 + gcol] = f2bf(acc[i][j][r]);
    }
  }
}

// ---------------------------------------------------------------------------
// Fused recurrent step: h_t @ [r|z|n|u]-packed weights (N'=2048) with GRU
// epilogue.  W1pk is k-chunked: [k/32][n(2048)][32] so staging is a fully
// contiguous 16 KB read per block per chunk.  u-gate written both f32 (Ut,
// for wk_ctx score precision) and bf16 (U16t, for day-attn Q loads).
// ---------------------------------------------------------------------------
__global__ __launch_bounds__(256) void step_fused(
    const float* __restrict__ Ht, const unsigned short* __restrict__ W1pk,
    const unsigned short* __restrict__ Gi_t,
    const float* __restrict__ b_ih, const float* __restrict__ b_hh,
    float* __restrict__ Hnext, float* __restrict__ Ut,
    unsigned short* __restrict__ U16t, int notLast)
{
  __shared__ __align__(16) char smem[46080];
  unsigned short* As = (unsigned short*)smem;            // 2 x 32 x 40
  unsigned short* Bs = (unsigned short*)(smem + 5120);   // 2 x 256 x 40
  float* Gbuf = (float*)smem;                            // overlay [3][32][72]

  const int tid = threadIdx.x;
  const int wave = tid >> 6, lane = tid & 63, quad = lane >> 4, l15 = lane & 15;
  const int rowBase = blockIdx.y * 32;
  const int colBase = blockIdx.x * 256;

  f32x4 acc[2][4];
#pragma unroll
  for (int i = 0; i < 2; ++i)
#pragma unroll
    for (int j = 0; j < 4; ++j)
#pragma unroll
      for (int r = 0; r < 4; ++r) acc[i][j][r] = 0.f;

  const int ar = tid >> 3;              // A row 0..31
  const int kqa = (tid & 7) * 4;        // 4 k's
  const float* aptr = Ht + (size_t)(rowBase + ar) * NH + kqa;
  const unsigned short* bbase = W1pk + (size_t)(colBase + tid) * 32;
  unsigned short* asd = As + ar * 40 + kqa;
  unsigned short* bsd = Bs + tid * 40;

  float4 xa = *(const float4*)aptr;
  uint4 bv0 = *(const uint4*)(bbase + 0);
  uint4 bv1 = *(const uint4*)(bbase + 8);
  uint4 bv2 = *(const uint4*)(bbase + 16);
  uint4 bv3 = *(const uint4*)(bbase + 24);

  int cur = 0;
  for (int k0 = 0; k0 < NH; k0 += 32) {
    ushort4 aw;
    aw.x = f2bf(xa.x); aw.y = f2bf(xa.y); aw.z = f2bf(xa.z); aw.w = f2bf(xa.w);
    *(ushort4*)(asd + cur * 1280) = aw;
    *(uint4*)(bsd + cur * 10240 + 0)  = bv0;
    *(uint4*)(bsd + cur * 10240 + 8)  = bv1;
    *(uint4*)(bsd + cur * 10240 + 16) = bv2;
    *(uint4*)(bsd + cur * 10240 + 24) = bv3;

    const int kn = k0 + 32;
    if (kn < NH) {
      xa = *(const float4*)(aptr + kn);
      const unsigned short* nb = bbase + (size_t)(kn >> 5) * (2048 * 32);
      bv0 = *(const uint4*)(nb + 0);
      bv1 = *(const uint4*)(nb + 8);
      bv2 = *(const uint4*)(nb + 16);
      bv3 = *(const uint4*)(nb + 24);
    }
    __syncthreads();

    const unsigned short* Ab = As + cur * 1280;
    const unsigned short* Bb = Bs + cur * 10240;
    const bf16x8 af0 = *(const bf16x8*)&Ab[(l15) * 40 + quad * 8];
    const bf16x8 af1 = *(const bf16x8*)&Ab[(16 + l15) * 40 + quad * 8];
#pragma unroll
    for (int j = 0; j < 4; ++j) {
      const bf16x8 bf = *(const bf16x8*)&Bb[(wave * 64 + j * 16 + l15) * 40 + quad * 8];
      acc[0][j] = __builtin_amdgcn_mfma_f32_16x16x32_bf16(af0, bf, acc[0][j], 0, 0, 0);
      acc[1][j] = __builtin_amdgcn_mfma_f32_16x16x32_bf16(af1, bf, acc[1][j], 0, 0, 0);
    }
    cur ^= 1;
  }
  __syncthreads();   // all LDS reads done before overlay writes

  // write gates: waves 0..2 -> Gbuf, wave 3 -> U (f32 + bf16)
#pragma unroll
  for (int i = 0; i < 2; ++i) {
#pragma unroll
    for (int j = 0; j < 4; ++j) {
#pragma unroll
      for (int r = 0; r < 4; ++r) {
        const int rl = 16 * i + quad * 4 + r;
        const int col = j * 16 + l15;
        if (wave == 3) {
          const float v = acc[i][j][r];
          const size_t off = (size_t)(rowBase + rl) * NH + blockIdx.x * 64 + col;
          Ut[off] = v;
          U16t[off] = f2bf(v);
        } else {
          Gbuf[(wave * 32 + rl) * 72 + col] = acc[i][j][r];
        }
      }
    }
  }
  __syncthreads();

  if (notLast) {
    const int rl = tid >> 3, c8 = (tid & 7) * 8;
    const int bg = rowBase + rl;
    const int jg = blockIdx.x * 64 + c8;
    const float* g0 = Gbuf + (0 * 32 + rl) * 72 + c8;
    const float* g1 = Gbuf + (1 * 32 + rl) * 72 + c8;
    const float* g2 = Gbuf + (2 * 32 + rl) * 72 + c8;
    const unsigned short* gp = Gi_t + (size_t)bg * 1536;
    float gr[8], gz[8], gn[8];
    { uint4 a = *(const uint4*)(gp + jg);        unp8(a, gr); }
    { uint4 a = *(const uint4*)(gp + 512 + jg);  unp8(a, gz); }
    { uint4 a = *(const uint4*)(gp + 1024 + jg); unp8(a, gn); }
    const float* hR = Ht + (size_t)bg * NH + jg;
    float* hW = Hnext + (size_t)bg * NH + jg;
    const float4 ho0 = *(const float4*)hR;
    const float4 ho1 = *(const float4*)(hR + 4);
    const float hov[8] = {ho0.x, ho0.y, ho0.z, ho0.w, ho1.x, ho1.y, ho1.z, ho1.w};
    float o[8];
#pragma unroll
    for (int c = 0; c < 8; ++c) {
      const int j = jg + c;
      const float ir  = gr[c] + b_ih[j];
      const float iz  = gz[c] + b_ih[512 + j];
      const float inn = gn[c] + b_ih[1024 + j];
      const float hr  = g0[c] + b_hh[j];
      const float hz  = g1[c] + b_hh[512 + j];
      const float hn  = g2[c] + b_hh[1024 + j];
      const float rg = 1.f / (1.f + expf(-(ir + hr)));
      const float zg = 1.f / (1.f + expf(-(iz + hz)));
      const float ng = tanhf(inn + rg * hn);
      o[c] = (1.f - zg) * ng + zg * hov[c];
    }
    *(float4*)hW = make_float4(o[0], o[1], o[2], o[3]);
    *(float4*)(hW + 4) = make_float4(o[4], o[5], o[6], o[7]);
  }
}

// ---------------------------------------------------------------------------
// MFMA day attention, one block per (b,d).  bf16 Q from U16 (no conversion),
// two-phase E staging: global->Erow coalesced, then Erow->ETs with
// s-consecutive mapping (conflict-free transposed writes).  ~75 KB LDS,
// 2 blocks/CU, 3 barriers.
// ---------------------------------------------------------------------------
__global__ __launch_bounds__(256) void day_attn_mfma(
    const float* __restrict__ enc, const int* __restrict__ numpairs,
    const unsigned short* __restrict__ U16, unsigned short* __restrict__ week)
{
  __shared__ unsigned short Erow[32 * 520];   // [s][h] (rows>=20 garbage, unread cols)
  __shared__ unsigned short ETs[512 * 36];    // [h][s], cols 20..31 zeroed
  __shared__ float S_lds[32 * 33];
  __shared__ unsigned short P_lds[32 * 40];

  const int tid = threadIdx.x;
  const int wave = tid >> 6, lane = tid & 63;
  const int quad = lane >> 4, l15 = lane & 15;
  const int b = blockIdx.x / ND, d = blockIdx.x % ND;
  const int mt = wave >> 1, nt = wave & 1;

  // zero ETs pad cols 20..31 (6 u32 per row) and all of P_lds
  for (int i = tid; i < 512 * 6; i += 256)
    *(unsigned*)&ETs[(i / 6) * 36 + 20 + (i % 6) * 2] = 0;
  for (int i = tid; i < 640; i += 256) ((unsigned*)P_lds)[i] = 0;

  // stage E_d row-major (coalesced f32 reads, bf16 LDS)
  const float* eb = enc + ((size_t)b * NS + d * DL) * NH;
  for (int f = tid; f < DL * NH / 4; f += 256) {
    const int s = f >> 7, h = (f & 127) * 4;
    const float4 v = *(const float4*)(eb + s * NH + h);
    ushort4 hs;
    hs.x = f2bf(v.x); hs.y = f2bf(v.y); hs.z = f2bf(v.z); hs.w = f2bf(v.w);
    *(ushort4*)&Erow[s * 520 + h] = hs;
  }

  // Q fragments straight from bf16 U16: row m = mt*16+l15 -> t (clamped)
  bf16x8 qa[16];
  {
    const int m = mt * 16 + l15;
    const int t = (m < NT + 1) ? m : NT;
    const unsigned short* qp = U16 + ((size_t)t * NB + b) * NH + quad * 8;
#pragma unroll
    for (int ks = 0; ks < 16; ++ks)
      qa[ks] = *(const bf16x8*)(qp + ks * 32);
  }
  __syncthreads();

  // build ETs from Erow: consecutive lanes take consecutive s -> writes are
  // byte-consecutive (no bank conflicts)
  for (int i = tid; i < 64 * DL; i += 256) {
    const int s = i % DL, h8 = i / DL;
    const uint4 v = *(const uint4*)&Erow[s * 520 + h8 * 8];
    const unsigned short* u = (const unsigned short*)&v;
#pragma unroll
    for (int c = 0; c < 8; ++c)
      ETs[(h8 * 8 + c) * 36 + s] = u[c];
  }

  // ---- QK^T : wave (mt,nt) computes a 16x16 S tile; B = row-major Erow ----
  f32x4 sacc = {0.f, 0.f, 0.f, 0.f};
#pragma unroll
  for (int ks = 0; ks < 16; ++ks) {
    const bf16x8 bf = *(const bf16x8*)&Erow[(nt * 16 + l15) * 520 + ks * 32 + quad * 8];
    sacc = __builtin_amdgcn_mfma_f32_16x16x32_bf16(qa[ks], bf, sacc, 0, 0, 0);
  }
#pragma unroll
  for (int r = 0; r < 4; ++r)
    S_lds[(mt * 16 + quad * 4 + r) * 33 + nt * 16 + l15] = sacc[r];
  __syncthreads();

  // ---- masked softmax over s (8 threads per row) ----
  {
    const int r = tid >> 3, c = tid & 7;
    const int base = b * NS + d * DL;
    float v0 = S_lds[r * 33 + c];
    if (numpairs[base + c] == 0) v0 = -1e9f;
    float v1 = S_lds[r * 33 + c + 8];
    if (numpairs[base + c + 8] == 0) v1 = -1e9f;
    float v2 = -1e30f;
    if (c < 4) {
      v2 = S_lds[r * 33 + c + 16];
      if (numpairs[base + c + 16] == 0) v2 = -1e9f;
    }
    float mx = fmaxf(fmaxf(v0, v1), v2);
    mx = fmaxf(mx, __shfl_xor(mx, 1));
    mx = fmaxf(mx, __shfl_xor(mx, 2));
    mx = fmaxf(mx, __shfl_xor(mx, 4));
    const float e0 = expf(v0 - mx), e1 = expf(v1 - mx);
    const float e2 = (c < 4) ? expf(v2 - mx) : 0.f;
    float sm = e0 + e1 + e2;
    sm += __shfl_xor(sm, 1);
    sm += __shfl_xor(sm, 2);
    sm += __shfl_xor(sm, 4);
    const float inv = 1.f / sm;
    P_lds[r * 40 + c] = f2bf(e0 * inv);
    P_lds[r * 40 + c + 8] = f2bf(e1 * inv);
    if (c < 4) P_lds[r * 40 + c + 16] = f2bf(e2 * inv);
  }
  __syncthreads();

  // ---- PV : wave (mt,nt) covers rows mt*16, h-cols nt*256 .. +255 ----
  const bf16x8 pa = *(const bf16x8*)&P_lds[(mt * 16 + l15) * 40 + quad * 8];
#pragma unroll
  for (int j = 0; j < 16; ++j) {
    const int hcol = nt * 256 + j * 16;
    const bf16x8 bf = *(const bf16x8*)&ETs[(hcol + l15) * 36 + quad * 8];
    f32x4 oacc = {0.f, 0.f, 0.f, 0.f};
    oacc = __builtin_amdgcn_mfma_f32_16x16x32_bf16(pa, bf, oacc, 0, 0, 0);
#pragma unroll
    for (int r = 0; r < 4; ++r) {
      const int t = mt * 16 + quad * 4 + r;
      if (t < NT)
        week[(((size_t)t * NB + b) * ND + d) * NH + hcol + l15] = f2bf(oacc[r]);
    }
  }
}

// ---------------------------------------------------------------------------
// Batched week attention + ctx + concat.  One block = (t, 16 b's).
// Scores use f32 U for precision.
// ---------------------------------------------------------------------------
__global__ __launch_bounds__(256) void wk_ctx(
    const float* __restrict__ U, const unsigned short* __restrict__ week,
    const float* __restrict__ H, unsigned short* __restrict__ concat)
{
  __shared__ float scS[16 * ND];
  __shared__ float awS[16 * ND];
  const int tid = threadIdx.x;
  const int t = blockIdx.x >> 5;
  const int grp = blockIdx.x & 31;
  const int b16 = tid >> 4, k16 = tid & 15;
  const int b = grp * 16 + b16;
  const float* vp = U + ((size_t)(t + 1) * NB + b) * NH + k16 * 32;
  const size_t wrow = ((size_t)t * NB + b) * ND;

  for (int d = 0; d < ND; ++d) {
    const unsigned short* wp = week + (wrow + d) * NH + k16 * 32;
    float p = 0.f;
#pragma unroll
    for (int q = 0; q < 8; ++q) {
      const float4 a = *(const float4*)(vp + q * 4);
      const ushort4 wv = *(const ushort4*)(wp + q * 4);
      p += a.x * bf2f(wv.x) + a.y * bf2f(wv.y) + a.z * bf2f(wv.z) + a.w * bf2f(wv.w);
    }
    p += __shfl_down(p, 8); p += __shfl_down(p, 4);
    p += __shfl_down(p, 2); p += __shfl_down(p, 1);
    if (k16 == 0) scS[b16 * ND + d] = p;
  }
  __syncthreads();
  if (tid < 16) {
    float s[ND], mx = -1e30f;
    for (int d = 0; d < ND; ++d) { s[d] = scS[tid * ND + d]; mx = fmaxf(mx, s[d]); }
    float sum = 0.f;
    for (int d = 0; d < ND; ++d) { float e = expf(s[d] - mx); s[d] = e; sum += e; }
    const float inv = 1.f / sum;
    for (int d = 0; d < ND; ++d) awS[tid * ND + d] = s[d] * inv;
  }
  __syncthreads();

  const int c0 = k16 * 32;
  const float* hp = H + ((size_t)(t + 1) * NB + b) * NH + c0;
  float aw[ND];
#pragma unroll
  for (int d = 0; d < ND; ++d) aw[d] = awS[b16 * ND + d];
  unsigned short* crow = concat + ((size_t)t * NB + b) * 1024;
#pragma unroll
  for (int q = 0; q < 8; ++q) {
    const int c = c0 + q * 4;
    const float4 hv = *(const float4*)(hp + q * 4);
    ushort4 hs;
    hs.x = f2bf(hv.x); hs.y = f2bf(hv.y); hs.z = f2bf(hv.z); hs.w = f2bf(hv.w);
    *(ushort4*)(crow + c) = hs;
    float4 cv = make_float4(0.f, 0.f, 0.f, 0.f);
#pragma unroll
    for (int d = 0; d < ND; ++d) {
      const ushort4 wv = *(const ushort4*)(week + (wrow + d) * NH + c);
      cv.x += aw[d] * bf2f(wv.x); cv.y += aw[d] * bf2f(wv.y);
      cv.z += aw[d] * bf2f(wv.z); cv.w += aw[d] * bf2f(wv.w);
    }
    ushort4 cs;
    cs.x = f2bf(cv.x); cs.y = f2bf(cv.y); cs.z = f2bf(cv.z); cs.w = f2bf(cv.w);
    *(ushort4*)(crow + 512 + c) = cs;
  }
}

// ---------------------------------------------------------------------------
// Single-pass log_softmax, row in registers.  Row r = t*NB+b -> out[b,t,:].
// ---------------------------------------------------------------------------
__global__ __launch_bounds__(256) void lsm_k(
    const float* __restrict__ logits, float* __restrict__ out)
{
  __shared__ float red[8];
  const int tid = threadIdx.x;
  const int wave = tid >> 6, lane = tid & 63;
  const int r = blockIdx.x;
  const int t = r >> 9, b = r & (NB - 1);
  const float* row = logits + (size_t)r * NVP;
  float v[4];
  float mx = -1e30f;
#pragma unroll
  for (int k = 0; k < 4; ++k) {
    const int c = tid + k * 256;
    v[k] = row[c];
    if (c < NV) mx = fmaxf(mx, v[k]);
  }
#pragma unroll
  for (int off = 32; off; off >>= 1) mx = fmaxf(mx, __shfl_xor(mx, off));
  if (lane == 0) red[wave] = mx;
  __syncthreads();
  mx = fmaxf(fmaxf(red[0], red[1]), fmaxf(red[2], red[3]));
  float s = 0.f;
#pragma unroll
  for (int k = 0; k < 4; ++k) {
    const int c = tid + k * 256;
    if (c < NV) s += expf(v[k] - mx);
  }
#pragma unroll
  for (int off = 32; off; off >>= 1) s += __shfl_xor(s, off);
  if (lane == 0) red[4 + wave] = s;
  __syncthreads();
  const float lse = mx + logf(red[4] + red[5] + red[6] + red[7]);
  float* orow = out + ((size_t)b * NT + t) * NV;
#pragma unroll
  for (int k = 0; k < 4; ++k) {
    const int c = tid + k * 256;
    if (c < NV) orow[c] = v[k] - lse;
  }
}

__global__ void write_last(const int* __restrict__ label, float* __restrict__ out2)
{
  const int b = blockIdx.x * 256 + threadIdx.x;
  if (b < NB) out2[b] = (float)label[b * LSTR + (NT - 1)];
}

// W1pk[(k/32)][n'][k%32]: n' = g*256 + gate*64 + (j - g*64); gate 0..2 =
// W_hh gates, gate 3 = Wa^T (u-gate).  k-chunked for coalesced staging.
__global__ __launch_bounds__(256) void pack_w1pk(
    const float* __restrict__ Whh, const float* __restrict__ Wa,
    unsigned short* __restrict__ W1pk)
{
  const int idx = blockIdx.x * 256 + threadIdx.x;
  const int np = idx >> 9, k = idx & 511;
  const int g = np >> 8, rem = np & 255, gate = rem >> 6, j = g * 64 + (rem & 63);
  float v;
  if (gate < 3) v = Whh[(size_t)(gate * 512 + j) * 512 + k];
  else          v = Wa[(size_t)k * 512 + j];
  W1pk[((size_t)(k >> 5) * 2048 + np) * 32 + (k & 31)] = f2bf(v);
}

__global__ __launch_bounds__(256) void cast4(
    const float4* __restrict__ in, ushort4* __restrict__ out, int n4)
{
  const int i = blockIdx.x * 256 + threadIdx.x;
  if (i < n4) {
    const float4 x = in[i];
    ushort4 r;
    r.x = f2bf(x.x); r.y = f2bf(x.y); r.z = f2bf(x.z); r.w = f2bf(x.w);
    out[i] = r;
  }
}

extern "C" void kernel_launch(void* const* d_in, const int* in_sizes, int n_in,
                              void* d_out, int out_size, void* d_ws, size_t ws_size,
                              hipStream_t stream)
{
  const float* enc_h  = (const float*)d_in[0];
  const float* enc    = (const float*)d_in[1];
  const int*   label  = (const int*)d_in[2];
  const int*   numprs = (const int*)d_in[3];
  const float* emb    = (const float*)d_in[4];
  const float* W_ih   = (const float*)d_in[5];
  const float* W_hh   = (const float*)d_in[6];
  const float* b_ih   = (const float*)d_in[7];
  const float* b_hh   = (const float*)d_in[8];
  const float* Wa     = (const float*)d_in[9];
  const float* wa_W   = (const float*)d_in[10];
  const float* fc_W   = (const float*)d_in[11];
  const float* fc_b   = (const float*)d_in[12];
  float* out = (float*)d_out;

  float* f = (float*)d_ws;
  float* H_all   = f; f += (size_t)(NT + 1) * NB * NH;   // 22 hidden states
  float* U_all   = f; f += (size_t)(NT + 1) * NB * NH;   // h_t @ Wa, f32
  float* logitsW = f; f += (size_t)NROW * NVP;
  unsigned short* us = (unsigned short*)f;
  unsigned short* U16    = us; us += (size_t)(NT + 1) * NB * NH;
  unsigned short* W1pk   = us; us += (size_t)2048 * 512;
  unsigned short* W3t    = us; us += (size_t)512 * 1024;
  unsigned short* W4t    = us; us += (size_t)NVP * 512;
  unsigned short* Wiht   = us; us += (size_t)1536 * 256;
  unsigned short* Gi     = us; us += (size_t)NT * NB * 1536;
  unsigned short* week   = us; us += (size_t)NT * NB * ND * NH;
  unsigned short* concatW= us; us += (size_t)NROW * 1024;
  unsigned short* aBuf   = us; us += (size_t)NROW * 512;

  const dim3 blk(256);
  const size_t BH = (size_t)NB * NH;

  hipMemcpyAsync(H_all, enc_h, BH * sizeof(float),
                 hipMemcpyDeviceToDevice, stream);

  // --- setup: weight packs/casts + Gi precompute ---
  pack_w1pk<<<dim3(2048 * 512 / 256), blk, 0, stream>>>(W_hh, Wa, W1pk);
  cast4<<<dim3(512 * 1024 / 4 / 256), blk, 0, stream>>>(
      (const float4*)wa_W, (ushort4*)W3t, 512 * 1024 / 4);
  cast4<<<dim3((NV * 512 / 4 + 255) / 256), blk, 0, stream>>>(
      (const float4*)fc_W, (ushort4*)W4t, NV * 512 / 4);
  hipMemsetAsync(W4t + (size_t)NV * 512, 0, (size_t)(NVP - NV) * 512 * 2, stream);
  cast4<<<dim3(1536 * 256 / 4 / 256), blk, 0, stream>>>(
      (const float4*)W_ih, (ushort4*)Wiht, 1536 * 256 / 4);
  gemm_gather<<<dim3(24, NT * 8), blk, 0, stream>>>(emb, Wiht, Gi, label);

  // --- recurrent phase: fused GEMM+GRU, one kernel per step ---
  // t = NT runs u-only (produces U[21] for week attention).
  for (int t = 0; t <= NT; ++t) {
    const int notLast = (t < NT) ? 1 : 0;
    const int tg = (t < NT) ? t : NT - 1;   // Gi index (unused when last)
    step_fused<<<dim3(8, 16), blk, 0, stream>>>(
        H_all + (size_t)t * BH, W1pk, Gi + (size_t)tg * NB * 1536,
        b_ih, b_hh,
        H_all + (size_t)(notLast ? t + 1 : t) * BH,
        U_all + (size_t)t * BH, U16 + (size_t)t * BH, notLast);
  }

  // --- batched tail ---
  day_attn_mfma<<<dim3(NB * ND), blk, 0, stream>>>(enc, numprs, U16, week);
  wk_ctx<<<dim3(NT * 32), blk, 0, stream>>>(U_all, week, H_all, concatW);
  gemm_k<1, 2, 1><<<dim3(8, NROW / 64), blk, 0, stream>>>(
      nullptr, concatW, W3t, nullptr, nullptr, aBuf, 1024, 1024, 512);
  gemm_k<1, 1, 0><<<dim3(16, NROW / 64), blk, 0, stream>>>(
      nullptr, aBuf, W4t, fc_b, logitsW, nullptr, 512, 512, NVP);
  lsm_k<<<dim3(NROW), blk, 0, stream>>>(logitsW, out);
  write_last<<<dim3(2), blk, 0, stream>>>(label, out + (size_t)NB * NT * NV);
}

// Round 8
// 674.998 us; speedup vs baseline: 2.7006x; 1.1626x over previous
//
#include <hip/hip_runtime.h>
#include <math.h>

typedef __attribute__((ext_vector_type(8))) short bf16x8;
typedef __attribute__((ext_vector_type(4))) float f32x4;

constexpr int NB = 512;
constexpr int NS = 140;
constexpr int NH = 512;
constexpr int NE = 256;
constexpr int NV = 1000;
constexpr int NVP = 1024;   // padded vocab
constexpr int NT = 21;
constexpr int ND = 7;
constexpr int DL = 20;
constexpr int SOS = 2;
constexpr int LSTR = NT + 1;
constexpr int NROW = NT * NB;       // 10752 batched (t,b) rows

__device__ __forceinline__ unsigned short f2bf(float f) {
  union { float f; unsigned u; } v; v.f = f;
  unsigned r = v.u + 0x7fffu + ((v.u >> 16) & 1u);
  return (unsigned short)(r >> 16);
}
__device__ __forceinline__ float bf2f(unsigned short h) {
  union { unsigned u; float f; } v; v.u = ((unsigned)h) << 16;
  return v.f;
}
__device__ __forceinline__ void unp8(uint4 v, float* o) {
  o[0] = bf2f((unsigned short)(v.x & 0xffffu)); o[1] = bf2f((unsigned short)(v.x >> 16));
  o[2] = bf2f((unsigned short)(v.y & 0xffffu)); o[3] = bf2f((unsigned short)(v.y >> 16));
  o[4] = bf2f((unsigned short)(v.z & 0xffffu)); o[5] = bf2f((unsigned short)(v.z >> 16));
  o[6] = bf2f((unsigned short)(v.w & 0xffffu)); o[7] = bf2f((unsigned short)(v.w >> 16));
}
__device__ __forceinline__ void unp4(uint2 v, float* o) {
  o[0] = bf2f((unsigned short)(v.x & 0xffffu)); o[1] = bf2f((unsigned short)(v.x >> 16));
  o[2] = bf2f((unsigned short)(v.y & 0xffffu)); o[3] = bf2f((unsigned short)(v.y >> 16));
}

// ---------------------------------------------------------------------------
// 64x64 MFMA tile body, double-buffered LDS (ONE barrier per K-chunk).
// A16: bf16 A. EPI: 0 none, 1 +bias (guarded col<NV), 2 tanh. OUT16: bf16 out.
// ---------------------------------------------------------------------------
template<int A16, int EPI, int OUT16>
__device__ __forceinline__ void gemm_body(
    const float* __restrict__ Af, const unsigned short* __restrict__ Ah,
    const unsigned short* __restrict__ Bt, const float* __restrict__ bias,
    float* __restrict__ C, unsigned short* __restrict__ C16,
    int K, int lda, int ldc, int bx, int by,
    unsigned short* As, unsigned short* Bs)
{
  const int tid = threadIdx.x;
  const int rowBase = by * 64, colBase = bx * 64;
  const int wave = tid >> 6, lane = tid & 63, quad = lane >> 4, l15 = lane & 15;
  const int rw = (wave & 1) * 32, cw = (wave >> 1) * 32;

  f32x4 acc[2][2];
#pragma unroll
  for (int i = 0; i < 2; ++i)
#pragma unroll
    for (int j = 0; j < 2; ++j)
#pragma unroll
      for (int r = 0; r < 4; ++r) acc[i][j][r] = 0.f;

  const int ar = tid >> 2;
  const int kq = (tid & 3) * 8;
  const float* aptrf = nullptr;
  const unsigned short* aptrh = nullptr;
  if (A16) aptrh = Ah + (size_t)(rowBase + ar) * lda + kq;
  else     aptrf = Af + (size_t)(rowBase + ar) * lda + kq;
  const unsigned short* bptr = Bt + (size_t)(colBase + ar) * K + kq;
  unsigned short* asd = &As[ar * 40 + kq];
  unsigned short* bsd = &Bs[ar * 40 + kq];

  float4 x0, x1;
  uint4 av;
  if (A16) {
    av = *(const uint4*)aptrh;
  } else {
    x0 = *(const float4*)aptrf; x1 = *(const float4*)(aptrf + 4);
  }
  uint4 bv = *(const uint4*)bptr;

  int cur = 0;
  for (int k0 = 0; k0 < K; k0 += 32) {
    uint4 aw;
    if (A16) {
      aw = av;
    } else {
      aw.x = (unsigned)f2bf(x0.x) | ((unsigned)f2bf(x0.y) << 16);
      aw.y = (unsigned)f2bf(x0.z) | ((unsigned)f2bf(x0.w) << 16);
      aw.z = (unsigned)f2bf(x1.x) | ((unsigned)f2bf(x1.y) << 16);
      aw.w = (unsigned)f2bf(x1.z) | ((unsigned)f2bf(x1.w) << 16);
    }
    *(uint4*)(asd + cur * 2560) = aw;
    *(uint4*)(bsd + cur * 2560) = bv;

    const int kn = k0 + 32;
    if (kn < K) {
      if (A16) {
        av = *(const uint4*)(aptrh + kn);
      } else {
        x0 = *(const float4*)(aptrf + kn);
        x1 = *(const float4*)(aptrf + kn + 4);
      }
      bv = *(const uint4*)(bptr + kn);
    }
    __syncthreads();

    const unsigned short* Ab = As + cur * 2560;
    const unsigned short* Bb = Bs + cur * 2560;
    const bf16x8 af0 = *(const bf16x8*)&Ab[(rw + l15) * 40 + quad * 8];
    const bf16x8 af1 = *(const bf16x8*)&Ab[(rw + 16 + l15) * 40 + quad * 8];
    const bf16x8 bf0 = *(const bf16x8*)&Bb[(cw + l15) * 40 + quad * 8];
    const bf16x8 bf1 = *(const bf16x8*)&Bb[(cw + 16 + l15) * 40 + quad * 8];
    acc[0][0] = __builtin_amdgcn_mfma_f32_16x16x32_bf16(af0, bf0, acc[0][0], 0, 0, 0);
    acc[0][1] = __builtin_amdgcn_mfma_f32_16x16x32_bf16(af0, bf1, acc[0][1], 0, 0, 0);
    acc[1][0] = __builtin_amdgcn_mfma_f32_16x16x32_bf16(af1, bf0, acc[1][0], 0, 0, 0);
    acc[1][1] = __builtin_amdgcn_mfma_f32_16x16x32_bf16(af1, bf1, acc[1][1], 0, 0, 0);
    cur ^= 1;
  }

#pragma unroll
  for (int i = 0; i < 2; ++i) {
    const int grow = rowBase + rw + 16 * i + quad * 4;
#pragma unroll
    for (int j = 0; j < 2; ++j) {
      const int gcol = colBase + cw + 16 * j + l15;
#pragma unroll
      for (int r = 0; r < 4; ++r) {
        float vo = acc[i][j][r];
        if (EPI == 1) vo += (gcol < NV) ? bias[gcol] : 0.f;
        if (EPI == 2) vo = tanhf(vo);
        if (OUT16) C16[(size_t)(grow + r) * ldc + gcol] = f2bf(vo);
        else       C[(size_t)(grow + r) * ldc + gcol] = vo;
      }
    }
  }
}

template<int A16, int EPI, int OUT16>
__global__ __launch_bounds__(256) void gemm_k(
    const float* __restrict__ Af, const unsigned short* __restrict__ Ah,
    const unsigned short* __restrict__ Bt, const float* __restrict__ bias,
    float* __restrict__ C, unsigned short* __restrict__ C16,
    int K, int lda, int ldc)
{
  __shared__ unsigned short As[2 * 64 * 40];
  __shared__ unsigned short Bs[2 * 64 * 40];
  gemm_body<A16, EPI, OUT16>(Af, Ah, Bt, bias, C, C16, K, lda, ldc,
                             blockIdx.x, blockIdx.y, As, Bs);
}

// ---------------------------------------------------------------------------
// Gi precompute: all 21 steps of emb[dec_t] @ W_ih^T, bf16 out. 2D grid.
// ---------------------------------------------------------------------------
__global__ __launch_bounds__(256) void gemm_gather(
    const float* __restrict__ emb, const unsigned short* __restrict__ Wiht,
    unsigned short* __restrict__ Gi, const int* __restrict__ label)
{
  __shared__ unsigned short As[64 * 40];
  __shared__ unsigned short Bs[64 * 40];
  const int tid = threadIdx.x;
  const int rowBase = blockIdx.y * 64, colBase = blockIdx.x * 64;
  const int wave = tid >> 6, lane = tid & 63, quad = lane >> 4, l15 = lane & 15;
  const int rw = (wave & 1) * 32, cw = (wave >> 1) * 32;
  const int K = 256;

  f32x4 acc[2][2];
#pragma unroll
  for (int i = 0; i < 2; ++i)
#pragma unroll
    for (int j = 0; j < 2; ++j)
#pragma unroll
      for (int r = 0; r < 4; ++r) acc[i][j][r] = 0.f;

  const int ar = tid >> 2;
  const int kq = (tid & 3) * 8;
  const int aRowG = rowBase + ar;
  const int t = aRowG >> 9;
  const int b = aRowG & 511;
  const int dec = (t == 0) ? SOS : label[b * LSTR + (t - 1)];
  const float* aptr = emb + (size_t)dec * NE + kq;
  const unsigned short* bptr = Wiht + (size_t)(colBase + ar) * K + kq;
  unsigned short* asd = &As[ar * 40 + kq];
  unsigned short* bsd = &Bs[ar * 40 + kq];

  float4 x0 = *(const float4*)aptr;
  float4 x1 = *(const float4*)(aptr + 4);
  uint4 bv = *(const uint4*)bptr;

  for (int k0 = 0; k0 < K; k0 += 32) {
    uint4 aw;
    aw.x = (unsigned)f2bf(x0.x) | ((unsigned)f2bf(x0.y) << 16);
    aw.y = (unsigned)f2bf(x0.z) | ((unsigned)f2bf(x0.w) << 16);
    aw.z = (unsigned)f2bf(x1.x) | ((unsigned)f2bf(x1.y) << 16);
    aw.w = (unsigned)f2bf(x1.z) | ((unsigned)f2bf(x1.w) << 16);
    *(uint4*)asd = aw;
    *(uint4*)bsd = bv;
    __syncthreads();
    const int kn = k0 + 32;
    if (kn < K) {
      x0 = *(const float4*)(aptr + kn);
      x1 = *(const float4*)(aptr + kn + 4);
      bv = *(const uint4*)(bptr + kn);
    }
    const bf16x8 af0 = *(const bf16x8*)&As[(rw + l15) * 40 + quad * 8];
    const bf16x8 af1 = *(const bf16x8*)&As[(rw + 16 + l15) * 40 + quad * 8];
    const bf16x8 bf0 = *(const bf16x8*)&Bs[(cw + l15) * 40 + quad * 8];
    const bf16x8 bf1 = *(const bf16x8*)&Bs[(cw + 16 + l15) * 40 + quad * 8];
    acc[0][0] = __builtin_amdgcn_mfma_f32_16x16x32_bf16(af0, bf0, acc[0][0], 0, 0, 0);
    acc[0][1] = __builtin_amdgcn_mfma_f32_16x16x32_bf16(af0, bf1, acc[0][1], 0, 0, 0);
    acc[1][0] = __builtin_amdgcn_mfma_f32_16x16x32_bf16(af1, bf0, acc[1][0], 0, 0, 0);
    acc[1][1] = __builtin_amdgcn_mfma_f32_16x16x32_bf16(af1, bf1, acc[1][1], 0, 0, 0);
    __syncthreads();
  }

#pragma unroll
  for (int i = 0; i < 2; ++i) {
    const int grow = rowBase + rw + 16 * i + quad * 4;
#pragma unroll
    for (int j = 0; j < 2; ++j) {
      const int gcol = colBase + cw + 16 * j + l15;
#pragma unroll
      for (int r = 0; r < 4; ++r)
        Gi[(size_t)(grow + r) * 1536 + gcol] = f2bf(acc[i][j][r]);
    }
  }
}

// ---------------------------------------------------------------------------
// Fused recurrent step, full-chip version: grid (16 G-groups, 16 row-tiles)
// = 256 blocks (one per CU).  Block = 32 rows x 128 cols (4 gates x 32 j's).
// W2 is k-chunked [k/32][G*128 + gate*32 + jj][k%32] -> 8 KB contiguous
// stage per chunk.  Wave w owns gate w; gates r,z,n exchanged via Gbuf.
// u-gate written f32 (Ut) + bf16 (U16t).
// ---------------------------------------------------------------------------
__global__ __launch_bounds__(256) void step_fused(
    const float* __restrict__ Ht, const unsigned short* __restrict__ W2,
    const unsigned short* __restrict__ Gi_t,
    const float* __restrict__ b_ih, const float* __restrict__ b_hh,
    float* __restrict__ Hnext, float* __restrict__ Ut,
    unsigned short* __restrict__ U16t, int notLast)
{
  __shared__ __align__(16) char smem[25600];
  unsigned short* As = (unsigned short*)smem;            // 2 x 32 x 40
  unsigned short* Bs = (unsigned short*)(smem + 5120);   // 2 x 128 x 40
  float* Gbuf = (float*)smem;                            // overlay [3][32][40]

  const int tid = threadIdx.x;
  const int wave = tid >> 6, lane = tid & 63, quad = lane >> 4, l15 = lane & 15;
  const int rowBase = blockIdx.y * 32;
  const int G = blockIdx.x;

  f32x4 acc[2][2];
#pragma unroll
  for (int i = 0; i < 2; ++i)
#pragma unroll
    for (int j = 0; j < 2; ++j)
#pragma unroll
      for (int r = 0; r < 4; ++r) acc[i][j][r] = 0.f;

  const int ar = tid >> 3;              // A row 0..31
  const int kqa = (tid & 7) * 4;        // 4 k's
  const float* aptr = Ht + (size_t)(rowBase + ar) * NH + kqa;
  const unsigned short* bsrc = W2 + (size_t)(G * 128) * 32 + (tid >> 1) * 32 + (tid & 1) * 16;
  unsigned short* asd = As + ar * 40 + kqa;
  unsigned short* bdst = Bs + (tid >> 1) * 40 + (tid & 1) * 16;

  float4 xa = *(const float4*)aptr;
  uint4 b0 = ((const uint4*)bsrc)[0];
  uint4 b1 = ((const uint4*)bsrc)[1];

  int cur = 0;
  for (int c = 0; c < 16; ++c) {
    ushort4 aw;
    aw.x = f2bf(xa.x); aw.y = f2bf(xa.y); aw.z = f2bf(xa.z); aw.w = f2bf(xa.w);
    *(ushort4*)(asd + cur * 1280) = aw;
    *(uint4*)(bdst + cur * 5120) = b0;
    *(uint4*)(bdst + cur * 5120 + 8) = b1;

    const int cn = c + 1;
    if (cn < 16) {
      xa = *(const float4*)(aptr + cn * 32);
      const unsigned short* nb = bsrc + (size_t)cn * (2048 * 32);
      b0 = ((const uint4*)nb)[0];
      b1 = ((const uint4*)nb)[1];
    }
    __syncthreads();

    const unsigned short* Ab = As + cur * 1280;
    const unsigned short* Bb = Bs + cur * 5120;
    const bf16x8 af0 = *(const bf16x8*)&Ab[(l15) * 40 + quad * 8];
    const bf16x8 af1 = *(const bf16x8*)&Ab[(16 + l15) * 40 + quad * 8];
#pragma unroll
    for (int j = 0; j < 2; ++j) {
      const bf16x8 bf = *(const bf16x8*)&Bb[(wave * 32 + j * 16 + l15) * 40 + quad * 8];
      acc[0][j] = __builtin_amdgcn_mfma_f32_16x16x32_bf16(af0, bf, acc[0][j], 0, 0, 0);
      acc[1][j] = __builtin_amdgcn_mfma_f32_16x16x32_bf16(af1, bf, acc[1][j], 0, 0, 0);
    }
    cur ^= 1;
  }
  __syncthreads();   // all LDS reads done before Gbuf overlay writes

  // gates r,z,n -> Gbuf (waves 0..2); u-gate -> U (f32 + bf16, wave 3)
#pragma unroll
  for (int i = 0; i < 2; ++i) {
#pragma unroll
    for (int j = 0; j < 2; ++j) {
#pragma unroll
      for (int r = 0; r < 4; ++r) {
        const int rl = 16 * i + quad * 4 + r;
        const int jj = j * 16 + l15;
        const float v = acc[i][j][r];
        if (wave == 3) {
          const size_t off = (size_t)(rowBase + rl) * NH + G * 32 + jj;
          Ut[off] = v;
          U16t[off] = f2bf(v);
        } else {
          Gbuf[(wave * 32 + rl) * 40 + jj] = v;
        }
      }
    }
  }
  __syncthreads();

  if (notLast) {
    const int rl = tid >> 3, c4 = (tid & 7) * 4;
    const int bg = rowBase + rl;
    const int j0 = G * 32 + c4;
    const float4 g0 = *(const float4*)(Gbuf + (0 * 32 + rl) * 40 + c4);
    const float4 g1 = *(const float4*)(Gbuf + (1 * 32 + rl) * 40 + c4);
    const float4 g2 = *(const float4*)(Gbuf + (2 * 32 + rl) * 40 + c4);
    const unsigned short* gp = Gi_t + (size_t)bg * 1536;
    float gr[4], gz[4], gn[4];
    { uint2 a = *(const uint2*)(gp + j0);        unp4(a, gr); }
    { uint2 a = *(const uint2*)(gp + 512 + j0);  unp4(a, gz); }
    { uint2 a = *(const uint2*)(gp + 1024 + j0); unp4(a, gn); }
    const float4 bi0 = *(const float4*)(b_ih + j0);
    const float4 bi1 = *(const float4*)(b_ih + 512 + j0);
    const float4 bi2 = *(const float4*)(b_ih + 1024 + j0);
    const float4 bh0 = *(const float4*)(b_hh + j0);
    const float4 bh1 = *(const float4*)(b_hh + 512 + j0);
    const float4 bh2 = *(const float4*)(b_hh + 1024 + j0);
    const float4 ho = *(const float4*)(Ht + (size_t)bg * NH + j0);
    const float ghr[4] = {g0.x, g0.y, g0.z, g0.w};
    const float ghz[4] = {g1.x, g1.y, g1.z, g1.w};
    const float ghn[4] = {g2.x, g2.y, g2.z, g2.w};
    const float bi0a[4] = {bi0.x, bi0.y, bi0.z, bi0.w};
    const float bi1a[4] = {bi1.x, bi1.y, bi1.z, bi1.w};
    const float bi2a[4] = {bi2.x, bi2.y, bi2.z, bi2.w};
    const float bh0a[4] = {bh0.x, bh0.y, bh0.z, bh0.w};
    const float bh1a[4] = {bh1.x, bh1.y, bh1.z, bh1.w};
    const float bh2a[4] = {bh2.x, bh2.y, bh2.z, bh2.w};
    const float hov[4] = {ho.x, ho.y, ho.z, ho.w};
    float o[4];
#pragma unroll
    for (int c = 0; c < 4; ++c) {
      const float rg = 1.f / (1.f + expf(-(gr[c] + bi0a[c] + ghr[c] + bh0a[c])));
      const float zg = 1.f / (1.f + expf(-(gz[c] + bi1a[c] + ghz[c] + bh1a[c])));
      const float ng = tanhf(gn[c] + bi2a[c] + rg * (ghn[c] + bh2a[c]));
      o[c] = (1.f - zg) * ng + zg * hov[c];
    }
    *(float4*)(Hnext + (size_t)bg * NH + j0) = make_float4(o[0], o[1], o[2], o[3]);
  }
}

// ---------------------------------------------------------------------------
// MFMA day attention, one block per (b,d).  ~46 KB LDS -> 3 blocks/CU.
// Single smem block: Erow [20][520] (QK^T B reads rows>=20 land in ETs
// region -> garbage, masked), ETs [256][36] rebuilt per h-half (2-pass PV).
// ---------------------------------------------------------------------------
__global__ __launch_bounds__(256) void day_attn_mfma(
    const float* __restrict__ enc, const int* __restrict__ numpairs,
    const unsigned short* __restrict__ U16, unsigned short* __restrict__ week)
{
  __shared__ __align__(16) char smem[46016];
  unsigned short* Erow = (unsigned short*)smem;              // [20][520]
  unsigned short* ETs  = (unsigned short*)(smem + 20800);    // [256][36]
  float*          S_lds = (float*)(smem + 39232);            // [32][33]
  unsigned short* P_lds = (unsigned short*)(smem + 43456);   // [32][40]

  const int tid = threadIdx.x;
  const int wave = tid >> 6, lane = tid & 63;
  const int quad = lane >> 4, l15 = lane & 15;
  const int b = blockIdx.x / ND, d = blockIdx.x % ND;
  const int mt = wave >> 1, nt = wave & 1;

  // zero ETs pad cols 20..31 (6 u32 per row, 256 rows) and all of P_lds
  for (int i = tid; i < 256 * 6; i += 256)
    *(unsigned*)&ETs[(i / 6) * 36 + 20 + (i % 6) * 2] = 0;
  for (int i = tid; i < 640; i += 256) ((unsigned*)P_lds)[i] = 0;

  // stage E_d row-major (coalesced f32 reads, bf16 LDS)
  const float* eb = enc + ((size_t)b * NS + d * DL) * NH;
  for (int f = tid; f < DL * NH / 4; f += 256) {
    const int s = f >> 7, h = (f & 127) * 4;
    const float4 v = *(const float4*)(eb + s * NH + h);
    ushort4 hs;
    hs.x = f2bf(v.x); hs.y = f2bf(v.y); hs.z = f2bf(v.z); hs.w = f2bf(v.w);
    *(ushort4*)&Erow[s * 520 + h] = hs;
  }

  // Q fragments straight from bf16 U16: row m = mt*16+l15 -> t (clamped)
  bf16x8 qa[16];
  {
    const int m = mt * 16 + l15;
    const int t = (m < NT + 1) ? m : NT;
    const unsigned short* qp = U16 + ((size_t)t * NB + b) * NH + quad * 8;
#pragma unroll
    for (int ks = 0; ks < 16; ++ks)
      qa[ks] = *(const bf16x8*)(qp + ks * 32);
  }
  __syncthreads();

  // build ETs half 0 (h 0..255); runs alongside QK^T (independent)
  for (int i = tid; i < 32 * DL; i += 256) {
    const int s = i % DL, h8 = i / DL;
    const uint4 v = *(const uint4*)&Erow[s * 520 + h8 * 8];
    const unsigned short* u = (const unsigned short*)&v;
#pragma unroll
    for (int c = 0; c < 8; ++c)
      ETs[(h8 * 8 + c) * 36 + s] = u[c];
  }

  // ---- QK^T : wave (mt,nt) computes a 16x16 S tile; B = row-major Erow ----
  // (rows >= 20 read garbage from the ETs region; those S cols are unread)
  f32x4 sacc = {0.f, 0.f, 0.f, 0.f};
#pragma unroll
  for (int ks = 0; ks < 16; ++ks) {
    const bf16x8 bf = *(const bf16x8*)&Erow[(nt * 16 + l15) * 520 + ks * 32 + quad * 8];
    sacc = __builtin_amdgcn_mfma_f32_16x16x32_bf16(qa[ks], bf, sacc, 0, 0, 0);
  }
#pragma unroll
  for (int r = 0; r < 4; ++r)
    S_lds[(mt * 16 + quad * 4 + r) * 33 + nt * 16 + l15] = sacc[r];
  __syncthreads();

  // ---- masked softmax over s (8 threads per row) ----
  {
    const int r = tid >> 3, c = tid & 7;
    const int base = b * NS + d * DL;
    float v0 = S_lds[r * 33 + c];
    if (numpairs[base + c] == 0) v0 = -1e9f;
    float v1 = S_lds[r * 33 + c + 8];
    if (numpairs[base + c + 8] == 0) v1 = -1e9f;
    float v2 = -1e30f;
    if (c < 4) {
      v2 = S_lds[r * 33 + c + 16];
      if (numpairs[base + c + 16] == 0) v2 = -1e9f;
    }
    float mx = fmaxf(fmaxf(v0, v1), v2);
    mx = fmaxf(mx, __shfl_xor(mx, 1));
    mx = fmaxf(mx, __shfl_xor(mx, 2));
    mx = fmaxf(mx, __shfl_xor(mx, 4));
    const float e0 = expf(v0 - mx), e1 = expf(v1 - mx);
    const float e2 = (c < 4) ? expf(v2 - mx) : 0.f;
    float sm = e0 + e1 + e2;
    sm += __shfl_xor(sm, 1);
    sm += __shfl_xor(sm, 2);
    sm += __shfl_xor(sm, 4);
    const float inv = 1.f / sm;
    P_lds[r * 40 + c] = f2bf(e0 * inv);
    P_lds[r * 40 + c + 8] = f2bf(e1 * inv);
    if (c < 4) P_lds[r * 40 + c + 16] = f2bf(e2 * inv);
  }
  __syncthreads();

  // ---- PV in two h-halves (ETs rebuilt between) ----
  const bf16x8 pa = *(const bf16x8*)&P_lds[(mt * 16 + l15) * 40 + quad * 8];
#pragma unroll
  for (int p = 0; p < 2; ++p) {
    if (p == 1) {
      // rebuild ETs for h 256..511
      for (int i = tid; i < 32 * DL; i += 256) {
        const int s = i % DL, h8 = i / DL;
        const uint4 v = *(const uint4*)&Erow[s * 520 + 256 + h8 * 8];
        const unsigned short* u = (const unsigned short*)&v;
#pragma unroll
        for (int c = 0; c < 8; ++c)
          ETs[(h8 * 8 + c) * 36 + s] = u[c];
      }
      __syncthreads();
    }
#pragma unroll
    for (int j = 0; j < 8; ++j) {
      const int hl = nt * 128 + j * 16;
      const bf16x8 bf = *(const bf16x8*)&ETs[(hl + l15) * 36 + quad * 8];
      f32x4 oacc = {0.f, 0.f, 0.f, 0.f};
      oacc = __builtin_amdgcn_mfma_f32_16x16x32_bf16(pa, bf, oacc, 0, 0, 0);
#pragma unroll
      for (int r = 0; r < 4; ++r) {
        const int t = mt * 16 + quad * 4 + r;
        if (t < NT)
          week[(((size_t)t * NB + b) * ND + d) * NH + p * 256 + hl + l15] = f2bf(oacc[r]);
      }
    }
    if (p == 0) __syncthreads();   // PV half-0 reads done before rebuild
  }
}

// ---------------------------------------------------------------------------
// Batched week attention + ctx + concat.  One block = (t, 16 b's).
// Scores use f32 U for precision.
// ---------------------------------------------------------------------------
__global__ __launch_bounds__(256) void wk_ctx(
    const float* __restrict__ U, const unsigned short* __restrict__ week,
    const float* __restrict__ H, unsigned short* __restrict__ concat)
{
  __shared__ float scS[16 * ND];
  __shared__ float awS[16 * ND];
  const int tid = threadIdx.x;
  const int t = blockIdx.x >> 5;
  const int grp = blockIdx.x & 31;
  const int b16 = tid >> 4, k16 = tid & 15;
  const int b = grp * 16 + b16;
  const float* vp = U + ((size_t)(t + 1) * NB + b) * NH + k16 * 32;
  const size_t wrow = ((size_t)t * NB + b) * ND;

  for (int d = 0; d < ND; ++d) {
    const unsigned short* wp = week + (wrow + d) * NH + k16 * 32;
    float p = 0.f;
#pragma unroll
    for (int q = 0; q < 8; ++q) {
      const float4 a = *(const float4*)(vp + q * 4);
      const ushort4 wv = *(const ushort4*)(wp + q * 4);
      p += a.x * bf2f(wv.x) + a.y * bf2f(wv.y) + a.z * bf2f(wv.z) + a.w * bf2f(wv.w);
    }
    p += __shfl_down(p, 8); p += __shfl_down(p, 4);
    p += __shfl_down(p, 2); p += __shfl_down(p, 1);
    if (k16 == 0) scS[b16 * ND + d] = p;
  }
  __syncthreads();
  if (tid < 16) {
    float s[ND], mx = -1e30f;
    for (int d = 0; d < ND; ++d) { s[d] = scS[tid * ND + d]; mx = fmaxf(mx, s[d]); }
    float sum = 0.f;
    for (int d = 0; d < ND; ++d) { float e = expf(s[d] - mx); s[d] = e; sum += e; }
    const float inv = 1.f / sum;
    for (int d = 0; d < ND; ++d) awS[tid * ND + d] = s[d] * inv;
  }
  __syncthreads();

  const int c0 = k16 * 32;
  const float* hp = H + ((size_t)(t + 1) * NB + b) * NH + c0;
  float aw[ND];
#pragma unroll
  for (int d = 0; d < ND; ++d) aw[d] = awS[b16 * ND + d];
  unsigned short* crow = concat + ((size_t)t * NB + b) * 1024;
#pragma unroll
  for (int q = 0; q < 8; ++q) {
    const int c = c0 + q * 4;
    const float4 hv = *(const float4*)(hp + q * 4);
    ushort4 hs;
    hs.x = f2bf(hv.x); hs.y = f2bf(hv.y); hs.z = f2bf(hv.z); hs.w = f2bf(hv.w);
    *(ushort4*)(crow + c) = hs;
    float4 cv = make_float4(0.f, 0.f, 0.f, 0.f);
#pragma unroll
    for (int d = 0; d < ND; ++d) {
      const ushort4 wv = *(const ushort4*)(week + (wrow + d) * NH + c);
      cv.x += aw[d] * bf2f(wv.x); cv.y += aw[d] * bf2f(wv.y);
      cv.z += aw[d] * bf2f(wv.z); cv.w += aw[d] * bf2f(wv.w);
    }
    ushort4 cs;
    cs.x = f2bf(cv.x); cs.y = f2bf(cv.y); cs.z = f2bf(cv.z); cs.w = f2bf(cv.w);
    *(ushort4*)(crow + 512 + c) = cs;
  }
}

// ---------------------------------------------------------------------------
// Single-pass log_softmax, row in registers.  Row r = t*NB+b -> out[b,t,:].
// ---------------------------------------------------------------------------
__global__ __launch_bounds__(256) void lsm_k(
    const float* __restrict__ logits, float* __restrict__ out)
{
  __shared__ float red[8];
  const int tid = threadIdx.x;
  const int wave = tid >> 6, lane = tid & 63;
  const int r = blockIdx.x;
  const int t = r >> 9, b = r & (NB - 1);
  const float* row = logits + (size_t)r * NVP;
  float v[4];
  float mx = -1e30f;
#pragma unroll
  for (int k = 0; k < 4; ++k) {
    const int c = tid + k * 256;
    v[k] = row[c];
    if (c < NV) mx = fmaxf(mx, v[k]);
  }
#pragma unroll
  for (int off = 32; off; off >>= 1) mx = fmaxf(mx, __shfl_xor(mx, off));
  if (lane == 0) red[wave] = mx;
  __syncthreads();
  mx = fmaxf(fmaxf(red[0], red[1]), fmaxf(red[2], red[3]));
  float s = 0.f;
#pragma unroll
  for (int k = 0; k < 4; ++k) {
    const int c = tid + k * 256;
    if (c < NV) s += expf(v[k] - mx);
  }
#pragma unroll
  for (int off = 32; off; off >>= 1) s += __shfl_xor(s, off);
  if (lane == 0) red[4 + wave] = s;
  __syncthreads();
  const float lse = mx + logf(red[4] + red[5] + red[6] + red[7]);
  float* orow = out + ((size_t)b * NT + t) * NV;
#pragma unroll
  for (int k = 0; k < 4; ++k) {
    const int c = tid + k * 256;
    if (c < NV) orow[c] = v[k] - lse;
  }
}

__global__ void write_last(const int* __restrict__ label, float* __restrict__ out2)
{
  const int b = blockIdx.x * 256 + threadIdx.x;
  if (b < NB) out2[b] = (float)label[b * LSTR + (NT - 1)];
}

// W2[(k/32)][n''][k%32]: n'' = G*128 + gate*32 + jj, j = G*32 + jj;
// gate 0..2 = W_hh gate rows, gate 3 = Wa^T (u-gate).
__global__ __launch_bounds__(256) void pack_w2(
    const float* __restrict__ Whh, const float* __restrict__ Wa,
    unsigned short* __restrict__ W2)
{
  const int idx = blockIdx.x * 256 + threadIdx.x;
  const int np = idx >> 9, k = idx & 511;
  const int G = np >> 7, rem = np & 127, gate = rem >> 5, j = G * 32 + (rem & 31);
  float v;
  if (gate < 3) v = Whh[(size_t)(gate * 512 + j) * 512 + k];
  else          v = Wa[(size_t)k * 512 + j];
  W2[((size_t)(k >> 5) * 2048 + np) * 32 + (k & 31)] = f2bf(v);
}

__global__ __launch_bounds__(256) void cast4(
    const float4* __restrict__ in, ushort4* __restrict__ out, int n4)
{
  const int i = blockIdx.x * 256 + threadIdx.x;
  if (i < n4) {
    const float4 x = in[i];
    ushort4 r;
    r.x = f2bf(x.x); r.y = f2bf(x.y); r.z = f2bf(x.z); r.w = f2bf(x.w);
    out[i] = r;
  }
}

extern "C" void kernel_launch(void* const* d_in, const int* in_sizes, int n_in,
                              void* d_out, int out_size, void* d_ws, size_t ws_size,
                              hipStream_t stream)
{
  const float* enc_h  = (const float*)d_in[0];
  const float* enc    = (const float*)d_in[1];
  const int*   label  = (const int*)d_in[2];
  const int*   numprs = (const int*)d_in[3];
  const float* emb    = (const float*)d_in[4];
  const float* W_ih   = (const float*)d_in[5];
  const float* W_hh   = (const float*)d_in[6];
  const float* b_ih   = (const float*)d_in[7];
  const float* b_hh   = (const float*)d_in[8];
  const float* Wa     = (const float*)d_in[9];
  const float* wa_W   = (const float*)d_in[10];
  const float* fc_W   = (const float*)d_in[11];
  const float* fc_b   = (const float*)d_in[12];
  float* out = (float*)d_out;

  float* f = (float*)d_ws;
  float* H_all   = f; f += (size_t)(NT + 1) * NB * NH;   // 22 hidden states
  float* U_all   = f; f += (size_t)(NT + 1) * NB * NH;   // h_t @ Wa, f32
  float* logitsW = f; f += (size_t)NROW * NVP;
  unsigned short* us = (unsigned short*)f;
  unsigned short* U16    = us; us += (size_t)(NT + 1) * NB * NH;
  unsigned short* W2     = us; us += (size_t)2048 * 512;
  unsigned short* W3t    = us; us += (size_t)512 * 1024;
  unsigned short* W4t    = us; us += (size_t)NVP * 512;
  unsigned short* Wiht   = us; us += (size_t)1536 * 256;
  unsigned short* Gi     = us; us += (size_t)NT * NB * 1536;
  unsigned short* week   = us; us += (size_t)NT * NB * ND * NH;
  unsigned short* concatW= us; us += (size_t)NROW * 1024;
  unsigned short* aBuf   = us; us += (size_t)NROW * 512;

  const dim3 blk(256);
  const size_t BH = (size_t)NB * NH;

  hipMemcpyAsync(H_all, enc_h, BH * sizeof(float),
                 hipMemcpyDeviceToDevice, stream);

  // --- setup: weight packs/casts + Gi precompute ---
  pack_w2<<<dim3(2048 * 512 / 256), blk, 0, stream>>>(W_hh, Wa, W2);
  cast4<<<dim3(512 * 1024 / 4 / 256), blk, 0, stream>>>(
      (const float4*)wa_W, (ushort4*)W3t, 512 * 1024 / 4);
  cast4<<<dim3((NV * 512 / 4 + 255) / 256), blk, 0, stream>>>(
      (const float4*)fc_W, (ushort4*)W4t, NV * 512 / 4);
  hipMemsetAsync(W4t + (size_t)NV * 512, 0, (size_t)(NVP - NV) * 512 * 2, stream);
  cast4<<<dim3(1536 * 256 / 4 / 256), blk, 0, stream>>>(
      (const float4*)W_ih, (ushort4*)Wiht, 1536 * 256 / 4);
  gemm_gather<<<dim3(24, NT * 8), blk, 0, stream>>>(emb, Wiht, Gi, label);

  // --- recurrent phase: fused GEMM+GRU, one kernel per step, 256 blocks ---
  // t = NT runs u-only (produces U[21] for week attention).
  for (int t = 0; t <= NT; ++t) {
    const int notLast = (t < NT) ? 1 : 0;
    const int tg = (t < NT) ? t : NT - 1;   // Gi index (unused when last)
    step_fused<<<dim3(16, 16), blk, 0, stream>>>(
        H_all + (size_t)t * BH, W2, Gi + (size_t)tg * NB * 1536,
        b_ih, b_hh,
        H_all + (size_t)(notLast ? t + 1 : t) * BH,
        U_all + (size_t)t * BH, U16 + (size_t)t * BH, notLast);
  }

  // --- batched tail ---
  day_attn_mfma<<<dim3(NB * ND), blk, 0, stream>>>(enc, numprs, U16, week);
  wk_ctx<<<dim3(NT * 32), blk, 0, stream>>>(U_all, week, H_all, concatW);
  gemm_k<1, 2, 1><<<dim3(8, NROW / 64), blk, 0, stream>>>(
      nullptr, concatW, W3t, nullptr, nullptr, aBuf, 1024, 1024, 512);
  gemm_k<1, 1, 0><<<dim3(16, NROW / 64), blk, 0, stream>>>(
      nullptr, aBuf, W4t, fc_b, logitsW, nullptr, 512, 512, NVP);
  lsm_k<<<dim3(NROW), blk, 0, stream>>>(logitsW, out);
  write_last<<<dim3(2), blk, 0, stream>>>(label, out + (size_t)NB * NT * NV);
}

// Round 9
// 640.590 us; speedup vs baseline: 2.8457x; 1.0537x over previous
//
#include <hip/hip_runtime.h>
#include <math.h>

typedef __attribute__((ext_vector_type(8))) short bf16x8;
typedef __attribute__((ext_vector_type(4))) float f32x4;

constexpr int NB = 512;
constexpr int NS = 140;
constexpr int NH = 512;
constexpr int NE = 256;
constexpr int NV = 1000;
constexpr int NVP = 1024;   // padded vocab
constexpr int NT = 21;
constexpr int ND = 7;
constexpr int DL = 20;
constexpr int SOS = 2;
constexpr int LSTR = NT + 1;
constexpr int NROW = NT * NB;       // 10752 batched (t,b) rows
constexpr int UST = LSTR * NH;      // U16 b-major stride (22*512)

__device__ __forceinline__ unsigned short f2bf(float f) {
  union { float f; unsigned u; } v; v.f = f;
  unsigned r = v.u + 0x7fffu + ((v.u >> 16) & 1u);
  return (unsigned short)(r >> 16);
}
__device__ __forceinline__ float bf2f(unsigned short h) {
  union { unsigned u; float f; } v; v.u = ((unsigned)h) << 16;
  return v.f;
}
__device__ __forceinline__ void unp2(unsigned v, float* o) {
  o[0] = bf2f((unsigned short)(v & 0xffffu));
  o[1] = bf2f((unsigned short)(v >> 16));
}

// ---------------------------------------------------------------------------
// 64x64 MFMA tile body, double-buffered LDS (ONE barrier per K-chunk).
// A16: bf16 A. EPI: 0 none, 1 +bias (guarded col<NV), 2 tanh. OUT16: bf16 out.
// ---------------------------------------------------------------------------
template<int A16, int EPI, int OUT16>
__device__ __forceinline__ void gemm_body(
    const float* __restrict__ Af, const unsigned short* __restrict__ Ah,
    const unsigned short* __restrict__ Bt, const float* __restrict__ bias,
    float* __restrict__ C, unsigned short* __restrict__ C16,
    int K, int lda, int ldc, int bx, int by,
    unsigned short* As, unsigned short* Bs)
{
  const int tid = threadIdx.x;
  const int rowBase = by * 64, colBase = bx * 64;
  const int wave = tid >> 6, lane = tid & 63, quad = lane >> 4, l15 = lane & 15;
  const int rw = (wave & 1) * 32, cw = (wave >> 1) * 32;

  f32x4 acc[2][2];
#pragma unroll
  for (int i = 0; i < 2; ++i)
#pragma unroll
    for (int j = 0; j < 2; ++j)
#pragma unroll
      for (int r = 0; r < 4; ++r) acc[i][j][r] = 0.f;

  const int ar = tid >> 2;
  const int kq = (tid & 3) * 8;
  const float* aptrf = nullptr;
  const unsigned short* aptrh = nullptr;
  if (A16) aptrh = Ah + (size_t)(rowBase + ar) * lda + kq;
  else     aptrf = Af + (size_t)(rowBase + ar) * lda + kq;
  const unsigned short* bptr = Bt + (size_t)(colBase + ar) * K + kq;
  unsigned short* asd = &As[ar * 40 + kq];
  unsigned short* bsd = &Bs[ar * 40 + kq];

  float4 x0, x1;
  uint4 av;
  if (A16) {
    av = *(const uint4*)aptrh;
  } else {
    x0 = *(const float4*)aptrf; x1 = *(const float4*)(aptrf + 4);
  }
  uint4 bv = *(const uint4*)bptr;

  int cur = 0;
  for (int k0 = 0; k0 < K; k0 += 32) {
    uint4 aw;
    if (A16) {
      aw = av;
    } else {
      aw.x = (unsigned)f2bf(x0.x) | ((unsigned)f2bf(x0.y) << 16);
      aw.y = (unsigned)f2bf(x0.z) | ((unsigned)f2bf(x0.w) << 16);
      aw.z = (unsigned)f2bf(x1.x) | ((unsigned)f2bf(x1.y) << 16);
      aw.w = (unsigned)f2bf(x1.z) | ((unsigned)f2bf(x1.w) << 16);
    }
    *(uint4*)(asd + cur * 2560) = aw;
    *(uint4*)(bsd + cur * 2560) = bv;

    const int kn = k0 + 32;
    if (kn < K) {
      if (A16) {
        av = *(const uint4*)(aptrh + kn);
      } else {
        x0 = *(const float4*)(aptrf + kn);
        x1 = *(const float4*)(aptrf + kn + 4);
      }
      bv = *(const uint4*)(bptr + kn);
    }
    __syncthreads();

    const unsigned short* Ab = As + cur * 2560;
    const unsigned short* Bb = Bs + cur * 2560;
    const bf16x8 af0 = *(const bf16x8*)&Ab[(rw + l15) * 40 + quad * 8];
    const bf16x8 af1 = *(const bf16x8*)&Ab[(rw + 16 + l15) * 40 + quad * 8];
    const bf16x8 bf0 = *(const bf16x8*)&Bb[(cw + l15) * 40 + quad * 8];
    const bf16x8 bf1 = *(const bf16x8*)&Bb[(cw + 16 + l15) * 40 + quad * 8];
    acc[0][0] = __builtin_amdgcn_mfma_f32_16x16x32_bf16(af0, bf0, acc[0][0], 0, 0, 0);
    acc[0][1] = __builtin_amdgcn_mfma_f32_16x16x32_bf16(af0, bf1, acc[0][1], 0, 0, 0);
    acc[1][0] = __builtin_amdgcn_mfma_f32_16x16x32_bf16(af1, bf0, acc[1][0], 0, 0, 0);
    acc[1][1] = __builtin_amdgcn_mfma_f32_16x16x32_bf16(af1, bf1, acc[1][1], 0, 0, 0);
    cur ^= 1;
  }

#pragma unroll
  for (int i = 0; i < 2; ++i) {
    const int grow = rowBase + rw + 16 * i + quad * 4;
#pragma unroll
    for (int j = 0; j < 2; ++j) {
      const int gcol = colBase + cw + 16 * j + l15;
#pragma unroll
      for (int r = 0; r < 4; ++r) {
        float vo = acc[i][j][r];
        if (EPI == 1) vo += (gcol < NV) ? bias[gcol] : 0.f;
        if (EPI == 2) vo = tanhf(vo);
        if (OUT16) C16[(size_t)(grow + r) * ldc + gcol] = f2bf(vo);
        else       C[(size_t)(grow + r) * ldc + gcol] = vo;
      }
    }
  }
}

template<int A16, int EPI, int OUT16>
__global__ __launch_bounds__(256) void gemm_k(
    const float* __restrict__ Af, const unsigned short* __restrict__ Ah,
    const unsigned short* __restrict__ Bt, const float* __restrict__ bias,
    float* __restrict__ C, unsigned short* __restrict__ C16,
    int K, int lda, int ldc)
{
  __shared__ unsigned short As[2 * 64 * 40];
  __shared__ unsigned short Bs[2 * 64 * 40];
  gemm_body<A16, EPI, OUT16>(Af, Ah, Bt, bias, C, C16, K, lda, ldc,
                             blockIdx.x, blockIdx.y, As, Bs);
}

// ---------------------------------------------------------------------------
// Gi precompute: all 21 steps of emb[dec_t] @ W_ih^T, bf16 out. 2D grid.
// ---------------------------------------------------------------------------
__global__ __launch_bounds__(256) void gemm_gather(
    const float* __restrict__ emb, const unsigned short* __restrict__ Wiht,
    unsigned short* __restrict__ Gi, const int* __restrict__ label)
{
  __shared__ unsigned short As[64 * 40];
  __shared__ unsigned short Bs[64 * 40];
  const int tid = threadIdx.x;
  const int rowBase = blockIdx.y * 64, colBase = blockIdx.x * 64;
  const int wave = tid >> 6, lane = tid & 63, quad = lane >> 4, l15 = lane & 15;
  const int rw = (wave & 1) * 32, cw = (wave >> 1) * 32;
  const int K = 256;

  f32x4 acc[2][2];
#pragma unroll
  for (int i = 0; i < 2; ++i)
#pragma unroll
    for (int j = 0; j < 2; ++j)
#pragma unroll
      for (int r = 0; r < 4; ++r) acc[i][j][r] = 0.f;

  const int ar = tid >> 2;
  const int kq = (tid & 3) * 8;
  const int aRowG = rowBase + ar;
  const int t = aRowG >> 9;
  const int b = aRowG & 511;
  const int dec = (t == 0) ? SOS : label[b * LSTR + (t - 1)];
  const float* aptr = emb + (size_t)dec * NE + kq;
  const unsigned short* bptr = Wiht + (size_t)(colBase + ar) * K + kq;
  unsigned short* asd = &As[ar * 40 + kq];
  unsigned short* bsd = &Bs[ar * 40 + kq];

  float4 x0 = *(const float4*)aptr;
  float4 x1 = *(const float4*)(aptr + 4);
  uint4 bv = *(const uint4*)bptr;

  for (int k0 = 0; k0 < K; k0 += 32) {
    uint4 aw;
    aw.x = (unsigned)f2bf(x0.x) | ((unsigned)f2bf(x0.y) << 16);
    aw.y = (unsigned)f2bf(x0.z) | ((unsigned)f2bf(x0.w) << 16);
    aw.z = (unsigned)f2bf(x1.x) | ((unsigned)f2bf(x1.y) << 16);
    aw.w = (unsigned)f2bf(x1.z) | ((unsigned)f2bf(x1.w) << 16);
    *(uint4*)asd = aw;
    *(uint4*)bsd = bv;
    __syncthreads();
    const int kn = k0 + 32;
    if (kn < K) {
      x0 = *(const float4*)(aptr + kn);
      x1 = *(const float4*)(aptr + kn + 4);
      bv = *(const uint4*)(bptr + kn);
    }
    const bf16x8 af0 = *(const bf16x8*)&As[(rw + l15) * 40 + quad * 8];
    const bf16x8 af1 = *(const bf16x8*)&As[(rw + 16 + l15) * 40 + quad * 8];
    const bf16x8 bf0 = *(const bf16x8*)&Bs[(cw + l15) * 40 + quad * 8];
    const bf16x8 bf1 = *(const bf16x8*)&Bs[(cw + 16 + l15) * 40 + quad * 8];
    acc[0][0] = __builtin_amdgcn_mfma_f32_16x16x32_bf16(af0, bf0, acc[0][0], 0, 0, 0);
    acc[0][1] = __builtin_amdgcn_mfma_f32_16x16x32_bf16(af0, bf1, acc[0][1], 0, 0, 0);
    acc[1][0] = __builtin_amdgcn_mfma_f32_16x16x32_bf16(af1, bf0, acc[1][0], 0, 0, 0);
    acc[1][1] = __builtin_amdgcn_mfma_f32_16x16x32_bf16(af1, bf1, acc[1][1], 0, 0, 0);
    __syncthreads();
  }

#pragma unroll
  for (int i = 0; i < 2; ++i) {
    const int grow = rowBase + rw + 16 * i + quad * 4;
#pragma unroll
    for (int j = 0; j < 2; ++j) {
      const int gcol = colBase + cw + 16 * j + l15;
#pragma unroll
      for (int r = 0; r < 4; ++r)
        Gi[(size_t)(grow + r) * 1536 + gcol] = f2bf(acc[i][j][r]);
    }
  }
}

// ---------------------------------------------------------------------------
// Fused recurrent step: grid (32 G-groups, 16 row-tiles) = 512 blocks
// (2 per CU -> barrier stalls overlap).  Block = 32 rows x 64 cols
// (4 gates x 16 j), BK=64 (8 barriers/step).  A staged from bf16 H16
// (ping-pong, no f2bf in hot loop).  W2 k-chunked [k/64][G*64+gate*16+jj][64].
// u-gate -> U_all f32 (t-major) + U16 bf16 (b-major).
// ---------------------------------------------------------------------------
__global__ __launch_bounds__(256) void step_fused(
    const float* __restrict__ Ht, const unsigned short* __restrict__ Ht16,
    const unsigned short* __restrict__ W2,
    const unsigned short* __restrict__ Gi_t,
    const float* __restrict__ b_ih, const float* __restrict__ b_hh,
    float* __restrict__ Hnext, unsigned short* __restrict__ H16next,
    float* __restrict__ Ut, unsigned short* __restrict__ U16,
    int tIdx, int notLast)
{
  __shared__ __align__(16) char smem[27648];
  unsigned short* As = (unsigned short*)smem;            // 2 x 32 x 72
  unsigned short* Bs = (unsigned short*)(smem + 9216);   // 2 x 64 x 72
  float* Gbuf = (float*)smem;                            // overlay [3][32][20]

  const int tid = threadIdx.x;
  const int wave = tid >> 6, lane = tid & 63, quad = lane >> 4, l15 = lane & 15;
  const int rowBase = blockIdx.y * 32;
  const int G = blockIdx.x;
  const int j0 = G * 16;

  f32x4 acc[2];
#pragma unroll
  for (int i = 0; i < 2; ++i)
#pragma unroll
    for (int r = 0; r < 4; ++r) acc[i][r] = 0.f;

  // A stage: row = tid>>3, 8 u16 at k8 = (tid&7)*8
  const int arow = tid >> 3, ak = (tid & 7) * 8;
  const unsigned short* aptr = Ht16 + (size_t)(rowBase + arow) * NH + ak;
  unsigned short* asd = As + arow * 72 + ak;
  // B stage: n = tid>>2, 16 u16 at k16 = (tid&3)*16 (fully contiguous 8 KB)
  const int bn = tid >> 2, bk = (tid & 3) * 16;
  const unsigned short* bptr = W2 + ((size_t)(G * 64 + bn)) * 64 + bk;
  unsigned short* bsd = Bs + bn * 72 + bk;

  uint4 av = *(const uint4*)aptr;
  uint4 bv0 = ((const uint4*)bptr)[0];
  uint4 bv1 = ((const uint4*)bptr)[1];

  int cur = 0;
  for (int c = 0; c < 8; ++c) {
    *(uint4*)(asd + cur * 2304) = av;
    *(uint4*)(bsd + cur * 4608) = bv0;
    *(uint4*)(bsd + cur * 4608 + 8) = bv1;

    const int cn = c + 1;
    if (cn < 8) {
      av = *(const uint4*)(aptr + cn * 64);
      const unsigned short* nb = bptr + (size_t)cn * (2048 * 64);
      bv0 = ((const uint4*)nb)[0];
      bv1 = ((const uint4*)nb)[1];
    }
    __syncthreads();

    const unsigned short* Ab = As + cur * 2304;
    const unsigned short* Bb = Bs + cur * 4608;
#pragma unroll
    for (int s = 0; s < 2; ++s) {
      const bf16x8 af0 = *(const bf16x8*)&Ab[(l15) * 72 + s * 32 + quad * 8];
      const bf16x8 af1 = *(const bf16x8*)&Ab[(16 + l15) * 72 + s * 32 + quad * 8];
      const bf16x8 bf = *(const bf16x8*)&Bb[(wave * 16 + l15) * 72 + s * 32 + quad * 8];
      acc[0] = __builtin_amdgcn_mfma_f32_16x16x32_bf16(af0, bf, acc[0], 0, 0, 0);
      acc[1] = __builtin_amdgcn_mfma_f32_16x16x32_bf16(af1, bf, acc[1], 0, 0, 0);
    }
    cur ^= 1;
  }
  __syncthreads();   // all LDS reads done before Gbuf overlay writes

  // gates r,z,n -> Gbuf (waves 0..2); u-gate -> U f32 t-major + bf16 b-major
#pragma unroll
  for (int i = 0; i < 2; ++i) {
#pragma unroll
    for (int r = 0; r < 4; ++r) {
      const int rl = 16 * i + quad * 4 + r;
      const float v = acc[i][r];
      if (wave == 3) {
        const int bg = rowBase + rl;
        Ut[(size_t)bg * NH + j0 + l15] = v;
        U16[(size_t)bg * UST + tIdx * NH + j0 + l15] = f2bf(v);
      } else {
        Gbuf[(wave * 32 + rl) * 20 + l15] = v;
      }
    }
  }
  __syncthreads();

  if (notLast) {
    const int rl = tid >> 3, p2 = (tid & 7) * 2;
    const int bg = rowBase + rl;
    const int jg = j0 + p2;
    const float2 g0 = *(const float2*)(Gbuf + (0 * 32 + rl) * 20 + p2);
    const float2 g1 = *(const float2*)(Gbuf + (1 * 32 + rl) * 20 + p2);
    const float2 g2 = *(const float2*)(Gbuf + (2 * 32 + rl) * 20 + p2);
    const unsigned short* gp = Gi_t + (size_t)bg * 1536;
    float gr[2], gz[2], gn[2];
    unp2(*(const unsigned*)(gp + jg), gr);
    unp2(*(const unsigned*)(gp + 512 + jg), gz);
    unp2(*(const unsigned*)(gp + 1024 + jg), gn);
    const float2 bi0 = *(const float2*)(b_ih + jg);
    const float2 bi1 = *(const float2*)(b_ih + 512 + jg);
    const float2 bi2 = *(const float2*)(b_ih + 1024 + jg);
    const float2 bh0 = *(const float2*)(b_hh + jg);
    const float2 bh1 = *(const float2*)(b_hh + 512 + jg);
    const float2 bh2 = *(const float2*)(b_hh + 1024 + jg);
    const float2 ho = *(const float2*)(Ht + (size_t)bg * NH + jg);
    const float ghr[2] = {g0.x, g0.y}, ghz[2] = {g1.x, g1.y}, ghn[2] = {g2.x, g2.y};
    const float bi0a[2] = {bi0.x, bi0.y}, bi1a[2] = {bi1.x, bi1.y}, bi2a[2] = {bi2.x, bi2.y};
    const float bh0a[2] = {bh0.x, bh0.y}, bh1a[2] = {bh1.x, bh1.y}, bh2a[2] = {bh2.x, bh2.y};
    const float hov[2] = {ho.x, ho.y};
    float o[2];
#pragma unroll
    for (int c = 0; c < 2; ++c) {
      const float rg = 1.f / (1.f + expf(-(gr[c] + bi0a[c] + ghr[c] + bh0a[c])));
      const float zg = 1.f / (1.f + expf(-(gz[c] + bi1a[c] + ghz[c] + bh1a[c])));
      const float ng = tanhf(gn[c] + bi2a[c] + rg * (ghn[c] + bh2a[c]));
      o[c] = (1.f - zg) * ng + zg * hov[c];
    }
    *(float2*)(Hnext + (size_t)bg * NH + jg) = make_float2(o[0], o[1]);
    *(unsigned*)(H16next + (size_t)bg * NH + jg) =
        (unsigned)f2bf(o[0]) | ((unsigned)f2bf(o[1]) << 16);
  }
}

// ---------------------------------------------------------------------------
// MFMA day attention, one block per (b,d).  ~46 KB LDS -> 3 blocks/CU.
// Q from b-major U16 (contiguous 22.5 KB per b, L1/L2-resident across the
// 7 sibling d-blocks).  Erow [20][520]; ETs [256][36] rebuilt per h-half.
// ---------------------------------------------------------------------------
__global__ __launch_bounds__(256) void day_attn_mfma(
    const float* __restrict__ enc, const int* __restrict__ numpairs,
    const unsigned short* __restrict__ U16, unsigned short* __restrict__ week)
{
  __shared__ __align__(16) char smem[46016];
  unsigned short* Erow = (unsigned short*)smem;              // [20][520]
  unsigned short* ETs  = (unsigned short*)(smem + 20800);    // [256][36]
  float*          S_lds = (float*)(smem + 39232);            // [32][33]
  unsigned short* P_lds = (unsigned short*)(smem + 43456);   // [32][40]

  const int tid = threadIdx.x;
  const int wave = tid >> 6, lane = tid & 63;
  const int quad = lane >> 4, l15 = lane & 15;
  const int b = blockIdx.x / ND, d = blockIdx.x % ND;
  const int mt = wave >> 1, nt = wave & 1;

  // zero ETs pad cols 20..31 (6 u32 per row, 256 rows) and all of P_lds
  for (int i = tid; i < 256 * 6; i += 256)
    *(unsigned*)&ETs[(i / 6) * 36 + 20 + (i % 6) * 2] = 0;
  for (int i = tid; i < 640; i += 256) ((unsigned*)P_lds)[i] = 0;

  // stage E_d row-major (coalesced f32 reads, bf16 LDS)
  const float* eb = enc + ((size_t)b * NS + d * DL) * NH;
  for (int f = tid; f < DL * NH / 4; f += 256) {
    const int s = f >> 7, h = (f & 127) * 4;
    const float4 v = *(const float4*)(eb + s * NH + h);
    ushort4 hs;
    hs.x = f2bf(v.x); hs.y = f2bf(v.y); hs.z = f2bf(v.z); hs.w = f2bf(v.w);
    *(ushort4*)&Erow[s * 520 + h] = hs;
  }

  // Q fragments from b-major bf16 U16: row m = mt*16+l15 -> t (clamped);
  // the whole Q block for this b is a contiguous 22.5 KB chunk.
  bf16x8 qa[16];
  {
    const int m = mt * 16 + l15;
    const int t = (m < NT + 1) ? m : NT;
    const unsigned short* qp = U16 + (size_t)b * UST + t * NH + quad * 8;
#pragma unroll
    for (int ks = 0; ks < 16; ++ks)
      qa[ks] = *(const bf16x8*)(qp + ks * 32);
  }
  __syncthreads();

  // build ETs half 0 (h 0..255); runs alongside QK^T (independent)
  for (int i = tid; i < 32 * DL; i += 256) {
    const int s = i % DL, h8 = i / DL;
    const uint4 v = *(const uint4*)&Erow[s * 520 + h8 * 8];
    const unsigned short* u = (const unsigned short*)&v;
#pragma unroll
    for (int c = 0; c < 8; ++c)
      ETs[(h8 * 8 + c) * 36 + s] = u[c];
  }

  // ---- QK^T : wave (mt,nt) computes a 16x16 S tile; B = row-major Erow ----
  // (rows >= 20 read garbage from the ETs region; those S cols are unread)
  f32x4 sacc = {0.f, 0.f, 0.f, 0.f};
#pragma unroll
  for (int ks = 0; ks < 16; ++ks) {
    const bf16x8 bf = *(const bf16x8*)&Erow[(nt * 16 + l15) * 520 + ks * 32 + quad * 8];
    sacc = __builtin_amdgcn_mfma_f32_16x16x32_bf16(qa[ks], bf, sacc, 0, 0, 0);
  }
#pragma unroll
  for (int r = 0; r < 4; ++r)
    S_lds[(mt * 16 + quad * 4 + r) * 33 + nt * 16 + l15] = sacc[r];
  __syncthreads();

  // ---- masked softmax over s (8 threads per row) ----
  {
    const int r = tid >> 3, c = tid & 7;
    const int base = b * NS + d * DL;
    float v0 = S_lds[r * 33 + c];
    if (numpairs[base + c] == 0) v0 = -1e9f;
    float v1 = S_lds[r * 33 + c + 8];
    if (numpairs[base + c + 8] == 0) v1 = -1e9f;
    float v2 = -1e30f;
    if (c < 4) {
      v2 = S_lds[r * 33 + c + 16];
      if (numpairs[base + c + 16] == 0) v2 = -1e9f;
    }
    float mx = fmaxf(fmaxf(v0, v1), v2);
    mx = fmaxf(mx, __shfl_xor(mx, 1));
    mx = fmaxf(mx, __shfl_xor(mx, 2));
    mx = fmaxf(mx, __shfl_xor(mx, 4));
    const float e0 = expf(v0 - mx), e1 = expf(v1 - mx);
    const float e2 = (c < 4) ? expf(v2 - mx) : 0.f;
    float sm = e0 + e1 + e2;
    sm += __shfl_xor(sm, 1);
    sm += __shfl_xor(sm, 2);
    sm += __shfl_xor(sm, 4);
    const float inv = 1.f / sm;
    P_lds[r * 40 + c] = f2bf(e0 * inv);
    P_lds[r * 40 + c + 8] = f2bf(e1 * inv);
    if (c < 4) P_lds[r * 40 + c + 16] = f2bf(e2 * inv);
  }
  __syncthreads();

  // ---- PV in two h-halves (ETs rebuilt between) ----
  const bf16x8 pa = *(const bf16x8*)&P_lds[(mt * 16 + l15) * 40 + quad * 8];
#pragma unroll
  for (int p = 0; p < 2; ++p) {
    if (p == 1) {
      // rebuild ETs for h 256..511
      for (int i = tid; i < 32 * DL; i += 256) {
        const int s = i % DL, h8 = i / DL;
        const uint4 v = *(const uint4*)&Erow[s * 520 + 256 + h8 * 8];
        const unsigned short* u = (const unsigned short*)&v;
#pragma unroll
        for (int c = 0; c < 8; ++c)
          ETs[(h8 * 8 + c) * 36 + s] = u[c];
      }
      __syncthreads();
    }
#pragma unroll
    for (int j = 0; j < 8; ++j) {
      const int hl = nt * 128 + j * 16;
      const bf16x8 bf = *(const bf16x8*)&ETs[(hl + l15) * 36 + quad * 8];
      f32x4 oacc = {0.f, 0.f, 0.f, 0.f};
      oacc = __builtin_amdgcn_mfma_f32_16x16x32_bf16(pa, bf, oacc, 0, 0, 0);
#pragma unroll
      for (int r = 0; r < 4; ++r) {
        const int t = mt * 16 + quad * 4 + r;
        if (t < NT)
          week[(((size_t)t * NB + b) * ND + d) * NH + p * 256 + hl + l15] = f2bf(oacc[r]);
      }
    }
    if (p == 0) __syncthreads();   // PV half-0 reads done before rebuild
  }
}

// ---------------------------------------------------------------------------
// Batched week attention + ctx + concat.  One block = (t, 16 b's).
// Scores use f32 U for precision.
// ---------------------------------------------------------------------------
__global__ __launch_bounds__(256) void wk_ctx(
    const float* __restrict__ U, const unsigned short* __restrict__ week,
    const float* __restrict__ H, unsigned short* __restrict__ concat)
{
  __shared__ float scS[16 * ND];
  __shared__ float awS[16 * ND];
  const int tid = threadIdx.x;
  const int t = blockIdx.x >> 5;
  const int grp = blockIdx.x & 31;
  const int b16 = tid >> 4, k16 = tid & 15;
  const int b = grp * 16 + b16;
  const float* vp = U + ((size_t)(t + 1) * NB + b) * NH + k16 * 32;
  const size_t wrow = ((size_t)t * NB + b) * ND;

  for (int d = 0; d < ND; ++d) {
    const unsigned short* wp = week + (wrow + d) * NH + k16 * 32;
    float p = 0.f;
#pragma unroll
    for (int q = 0; q < 8; ++q) {
      const float4 a = *(const float4*)(vp + q * 4);
      const ushort4 wv = *(const ushort4*)(wp + q * 4);
      p += a.x * bf2f(wv.x) + a.y * bf2f(wv.y) + a.z * bf2f(wv.z) + a.w * bf2f(wv.w);
    }
    p += __shfl_down(p, 8); p += __shfl_down(p, 4);
    p += __shfl_down(p, 2); p += __shfl_down(p, 1);
    if (k16 == 0) scS[b16 * ND + d] = p;
  }
  __syncthreads();
  if (tid < 16) {
    float s[ND], mx = -1e30f;
    for (int d = 0; d < ND; ++d) { s[d] = scS[tid * ND + d]; mx = fmaxf(mx, s[d]); }
    float sum = 0.f;
    for (int d = 0; d < ND; ++d) { float e = expf(s[d] - mx); s[d] = e; sum += e; }
    const float inv = 1.f / sum;
    for (int d = 0; d < ND; ++d) awS[tid * ND + d] = s[d] * inv;
  }
  __syncthreads();

  const int c0 = k16 * 32;
  const float* hp = H + ((size_t)(t + 1) * NB + b) * NH + c0;
  float aw[ND];
#pragma unroll
  for (int d = 0; d < ND; ++d) aw[d] = awS[b16 * ND + d];
  unsigned short* crow = concat + ((size_t)t * NB + b) * 1024;
#pragma unroll
  for (int q = 0; q < 8; ++q) {
    const int c = c0 + q * 4;
    const float4 hv = *(const float4*)(hp + q * 4);
    ushort4 hs;
    hs.x = f2bf(hv.x); hs.y = f2bf(hv.y); hs.z = f2bf(hv.z); hs.w = f2bf(hv.w);
    *(ushort4*)(crow + c) = hs;
    float4 cv = make_float4(0.f, 0.f, 0.f, 0.f);
#pragma unroll
    for (int d = 0; d < ND; ++d) {
      const ushort4 wv = *(const ushort4*)(week + (wrow + d) * NH + c);
      cv.x += aw[d] * bf2f(wv.x); cv.y += aw[d] * bf2f(wv.y);
      cv.z += aw[d] * bf2f(wv.z); cv.w += aw[d] * bf2f(wv.w);
    }
    ushort4 cs;
    cs.x = f2bf(cv.x); cs.y = f2bf(cv.y); cs.z = f2bf(cv.z); cs.w = f2bf(cv.w);
    *(ushort4*)(crow + 512 + c) = cs;
  }
}

// ---------------------------------------------------------------------------
// Single-pass log_softmax, row in registers.  Row r = t*NB+b -> out[b,t,:].
// ---------------------------------------------------------------------------
__global__ __launch_bounds__(256) void lsm_k(
    const float* __restrict__ logits, float* __restrict__ out)
{
  __shared__ float red[8];
  const int tid = threadIdx.x;
  const int wave = tid >> 6, lane = tid & 63;
  const int r = blockIdx.x;
  const int t = r >> 9, b = r & (NB - 1);
  const float* row = logits + (size_t)r * NVP;
  float v[4];
  float mx = -1e30f;
#pragma unroll
  for (int k = 0; k < 4; ++k) {
    const int c = tid + k * 256;
    v[k] = row[c];
    if (c < NV) mx = fmaxf(mx, v[k]);
  }
#pragma unroll
  for (int off = 32; off; off >>= 1) mx = fmaxf(mx, __shfl_xor(mx, off));
  if (lane == 0) red[wave] = mx;
  __syncthreads();
  mx = fmaxf(fmaxf(red[0], red[1]), fmaxf(red[2], red[3]));
  float s = 0.f;
#pragma unroll
  for (int k = 0; k < 4; ++k) {
    const int c = tid + k * 256;
    if (c < NV) s += expf(v[k] - mx);
  }
#pragma unroll
  for (int off = 32; off; off >>= 1) s += __shfl_xor(s, off);
  if (lane == 0) red[4 + wave] = s;
  __syncthreads();
  const float lse = mx + logf(red[4] + red[5] + red[6] + red[7]);
  float* orow = out + ((size_t)b * NT + t) * NV;
#pragma unroll
  for (int k = 0; k < 4; ++k) {
    const int c = tid + k * 256;
    if (c < NV) orow[c] = v[k] - lse;
  }
}

__global__ void write_last(const int* __restrict__ label, float* __restrict__ out2)
{
  const int b = blockIdx.x * 256 + threadIdx.x;
  if (b < NB) out2[b] = (float)label[b * LSTR + (NT - 1)];
}

// W2[(k/64)][n''][k%64]: n'' = G*64 + gate*16 + jj, j = G*16 + jj;
// gate 0..2 = W_hh gate rows, gate 3 = Wa^T (u-gate).
__global__ __launch_bounds__(256) void pack_w2(
    const float* __restrict__ Whh, const float* __restrict__ Wa,
    unsigned short* __restrict__ W2)
{
  const int idx = blockIdx.x * 256 + threadIdx.x;
  const int np = idx >> 9, k = idx & 511;
  const int G = np >> 6, rem = np & 63, gate = rem >> 4, j = G * 16 + (rem & 15);
  float v;
  if (gate < 3) v = Whh[(size_t)(gate * 512 + j) * 512 + k];
  else          v = Wa[(size_t)k * 512 + j];
  W2[((size_t)(k >> 6) * 2048 + np) * 64 + (k & 63)] = f2bf(v);
}

__global__ __launch_bounds__(256) void cast4(
    const float4* __restrict__ in, ushort4* __restrict__ out, int n4)
{
  const int i = blockIdx.x * 256 + threadIdx.x;
  if (i < n4) {
    const float4 x = in[i];
    ushort4 r;
    r.x = f2bf(x.x); r.y = f2bf(x.y); r.z = f2bf(x.z); r.w = f2bf(x.w);
    out[i] = r;
  }
}

extern "C" void kernel_launch(void* const* d_in, const int* in_sizes, int n_in,
                              void* d_out, int out_size, void* d_ws, size_t ws_size,
                              hipStream_t stream)
{
  const float* enc_h  = (const float*)d_in[0];
  const float* enc    = (const float*)d_in[1];
  const int*   label  = (const int*)d_in[2];
  const int*   numprs = (const int*)d_in[3];
  const float* emb    = (const float*)d_in[4];
  const float* W_ih   = (const float*)d_in[5];
  const float* W_hh   = (const float*)d_in[6];
  const float* b_ih   = (const float*)d_in[7];
  const float* b_hh   = (const float*)d_in[8];
  const float* Wa     = (const float*)d_in[9];
  const float* wa_W   = (const float*)d_in[10];
  const float* fc_W   = (const float*)d_in[11];
  const float* fc_b   = (const float*)d_in[12];
  float* out = (float*)d_out;

  float* f = (float*)d_ws;
  float* H_all   = f; f += (size_t)(NT + 1) * NB * NH;   // 22 hidden states
  float* U_all   = f; f += (size_t)(NT + 1) * NB * NH;   // h_t @ Wa, f32 t-major
  float* logitsW = f; f += (size_t)NROW * NVP;
  unsigned short* us = (unsigned short*)f;
  unsigned short* U16    = us; us += (size_t)NB * UST;   // bf16, b-major
  unsigned short* H16a   = us; us += (size_t)NB * NH;
  unsigned short* H16b   = us; us += (size_t)NB * NH;
  unsigned short* W2     = us; us += (size_t)2048 * 512;
  unsigned short* W3t    = us; us += (size_t)512 * 1024;
  unsigned short* W4t    = us; us += (size_t)NVP * 512;
  unsigned short* Wiht   = us; us += (size_t)1536 * 256;
  unsigned short* Gi     = us; us += (size_t)NT * NB * 1536;
  unsigned short* week   = us; us += (size_t)NT * NB * ND * NH;
  unsigned short* concatW= us; us += (size_t)NROW * 1024;
  unsigned short* aBuf   = us; us += (size_t)NROW * 512;
  unsigned short* H16p[2] = {H16a, H16b};

  const dim3 blk(256);
  const size_t BH = (size_t)NB * NH;

  hipMemcpyAsync(H_all, enc_h, BH * sizeof(float),
                 hipMemcpyDeviceToDevice, stream);

  // --- setup: weight packs/casts + Gi precompute ---
  pack_w2<<<dim3(2048 * 512 / 256), blk, 0, stream>>>(W_hh, Wa, W2);
  cast4<<<dim3(BH / 4 / 256), blk, 0, stream>>>(
      (const float4*)enc_h, (ushort4*)H16a, (int)(BH / 4));
  cast4<<<dim3(512 * 1024 / 4 / 256), blk, 0, stream>>>(
      (const float4*)wa_W, (ushort4*)W3t, 512 * 1024 / 4);
  cast4<<<dim3((NV * 512 / 4 + 255) / 256), blk, 0, stream>>>(
      (const float4*)fc_W, (ushort4*)W4t, NV * 512 / 4);
  hipMemsetAsync(W4t + (size_t)NV * 512, 0, (size_t)(NVP - NV) * 512 * 2, stream);
  cast4<<<dim3(1536 * 256 / 4 / 256), blk, 0, stream>>>(
      (const float4*)W_ih, (ushort4*)Wiht, 1536 * 256 / 4);
  gemm_gather<<<dim3(24, NT * 8), blk, 0, stream>>>(emb, Wiht, Gi, label);

  // --- recurrent phase: fused GEMM+GRU, 512 blocks (2/CU) per step ---
  // t = NT runs u-only (produces U[21] for week attention).
  for (int t = 0; t <= NT; ++t) {
    const int notLast = (t < NT) ? 1 : 0;
    const int tg = (t < NT) ? t : NT - 1;   // Gi index (unused when last)
    step_fused<<<dim3(32, 16), blk, 0, stream>>>(
        H_all + (size_t)t * BH, H16p[t & 1], W2,
        Gi + (size_t)tg * NB * 1536, b_ih, b_hh,
        H_all + (size_t)(notLast ? t + 1 : t) * BH, H16p[(t + 1) & 1],
        U_all + (size_t)t * BH, U16, t, notLast);
  }

  // --- batched tail ---
  day_attn_mfma<<<dim3(NB * ND), blk, 0, stream>>>(enc, numprs, U16, week);
  wk_ctx<<<dim3(NT * 32), blk, 0, stream>>>(U_all, week, H_all, concatW);
  gemm_k<1, 2, 1><<<dim3(8, NROW / 64), blk, 0, stream>>>(
      nullptr, concatW, W3t, nullptr, nullptr, aBuf, 1024, 1024, 512);
  gemm_k<1, 1, 0><<<dim3(16, NROW / 64), blk, 0, stream>>>(
      nullptr, aBuf, W4t, fc_b, logitsW, nullptr, 512, 512, NVP);
  lsm_k<<<dim3(NROW), blk, 0, stream>>>(logitsW, out);
  write_last<<<dim3(2), blk, 0, stream>>>(label, out + (size_t)NB * NT * NV);
}